// Round 1
// baseline (549.634 us; speedup 1.0000x reference)
//
#include <hip/hip_runtime.h>

#define BB 64
#define NN 1000
#define NP 1024
#define DD 512
#define HH 8
#define SS 20
#define NEGV -1e9f

typedef float v4f __attribute__((ext_vector_type(4)));
typedef short v8s __attribute__((ext_vector_type(8)));

static __device__ __forceinline__ short f2bf(float f) {
    unsigned u = __builtin_bit_cast(unsigned, f);
    u = (u + 0x7fffu + ((u >> 16) & 1u)) >> 16;
    return (short)u;
}

// ---------------- K0a: f32 [R][C] -> bf16 transposed [C][R] ----------------
__global__ void transpose_bf16(const float* __restrict__ src, short* __restrict__ dst,
                               int R, int C) {
    __shared__ float t[32][33];
    int c0 = blockIdx.x * 32, r0 = blockIdx.y * 32;
    int x = threadIdx.x & 31, y = threadIdx.x >> 5;  // y in 0..7
    for (int k = 0; k < 32; k += 8)
        t[y + k][x] = src[(long)(r0 + y + k) * C + c0 + x];
    __syncthreads();
    for (int k = 0; k < 32; k += 8)
        dst[(long)(c0 + y + k) * R + r0 + x] = f2bf(t[x][y + k]);
}

// ---------------- K0b: embeddings f32 -> bf16 ----------------
__global__ void cvt_bf16(const float* __restrict__ src, short* __restrict__ dst, int n8) {
    int i = blockIdx.x * 256 + threadIdx.x;
    if (i >= n8) return;
    long o = (long)i * 8;
    v4f a = *(const v4f*)(src + o);
    v4f b = *(const v4f*)(src + o + 4);
    short tmp[8] = {f2bf(a.x), f2bf(a.y), f2bf(a.z), f2bf(a.w),
                    f2bf(b.x), f2bf(b.y), f2bf(b.z), f2bf(b.w)};
    *(uint4*)(dst + o) = *(uint4*)tmp;
}

// ---------------- K1: kvl[64000][1536] = embb[64000][512] @ W_kvl ----------------
// Wt = W_kvl^T as bf16 [1536][512]. 128x128 tile, BK=32, 4 waves of 64x64.
__global__ __launch_bounds__(256) void gemm_kvl(const short* __restrict__ embb,
                                                const short* __restrict__ Wt,
                                                short* __restrict__ kvl) {
    __shared__ __align__(16) short sm[17408];  // 34816 B: staging 10240 sh | repack 17408 sh
    short* As = sm;            // [128][40] (m-major, k contiguous, pad 40 -> 2-way free)
    short* Bs = sm + 128 * 40; // [128][40] (col-major, k contiguous)
    int tid = threadIdx.x;
    int n0 = blockIdx.x * 128, m0 = blockIdx.y * 128;  // n fastest: A-tile L2 reuse
    int wid = tid >> 6, lane = tid & 63, quad = lane >> 4, l16 = lane & 15;
    int wm = wid & 1, wn = wid >> 1;
    int srow = tid >> 2, sk8 = (tid & 3) * 8;  // staging: 64 rows/pass, 8 bf16/thread
    v4f acc[4][4] = {};
    for (int kk = 0; kk < 512; kk += 32) {
        #pragma unroll
        for (int p = 0; p < 2; ++p) {
            int r = srow + p * 64;
            *(uint4*)(As + r * 40 + sk8) =
                *(const uint4*)(embb + (long)(m0 + r) * 512 + kk + sk8);
            *(uint4*)(Bs + r * 40 + sk8) =
                *(const uint4*)(Wt + (long)(n0 + r) * 512 + kk + sk8);
        }
        __syncthreads();
        v8s af[4], bf[4];
        #pragma unroll
        for (int i = 0; i < 4; ++i)
            af[i] = *(const v8s*)(As + (wm * 64 + i * 16 + l16) * 40 + quad * 8);
        #pragma unroll
        for (int j = 0; j < 4; ++j)
            bf[j] = *(const v8s*)(Bs + (wn * 64 + j * 16 + l16) * 40 + quad * 8);
        #pragma unroll
        for (int i = 0; i < 4; ++i)
            #pragma unroll
            for (int j = 0; j < 4; ++j)
                acc[i][j] = __builtin_amdgcn_mfma_f32_16x16x32_bf16(af[i], bf[j], acc[i][j], 0, 0, 0);
        __syncthreads();
    }
    // epilogue: repack through LDS so global stores are 128B/wave coalesced
    short* rp = sm + wid * (64 * 68);
    #pragma unroll
    for (int i = 0; i < 4; ++i)
        #pragma unroll
        for (int j = 0; j < 4; ++j)
            #pragma unroll
            for (int r = 0; r < 4; ++r)
                rp[(i * 16 + quad * 4 + r) * 68 + j * 16 + l16] = f2bf(acc[i][j][r]);
    __syncthreads();
    long rowbase = (long)(m0 + wm * 64) * 1536 + n0 + wn * 64;
    for (int r = 0; r < 64; ++r)
        kvl[rowbase + (long)r * 1536 + lane] = rp[r * 68 + lane];
}

// ---------------- K2a: compat[(b*8+h)*20+s][1024] = (Q . K^T)/8 ----------------
__global__ __launch_bounds__(256) void qk_compat(const float* __restrict__ q,
                                                 const short* __restrict__ kvl,
                                                 float* __restrict__ compat) {
    int b = blockIdx.x, h = blockIdx.y;
    __shared__ __align__(16) short qs[32 * 72];
    int tid = threadIdx.x;
    for (int i = tid; i < 32 * 64; i += 256) {
        int row = i >> 6, col = i & 63;
        float v = (row < SS) ? q[((long)b * SS + row) * DD + h * 64 + col] * 0.125f : 0.f;
        qs[row * 72 + col] = f2bf(v);
    }
    __syncthreads();
    int wid = tid >> 6, lane = tid & 63, quad = lane >> 4, l16 = lane & 15;
    v8s af[2][2];
    #pragma unroll
    for (int mt = 0; mt < 2; ++mt)
        #pragma unroll
        for (int ks = 0; ks < 2; ++ks)
            af[mt][ks] = *(const v8s*)(qs + (mt * 16 + l16) * 72 + ks * 32 + quad * 8);
    for (int t = 0; t < 16; ++t) {
        int nt = wid * 16 + t;
        int n = nt * 16 + l16;
        int nc = n < NN ? n : NN - 1;
        const short* kp = kvl + ((long)b * NN + nc) * 1536 + h * 64 + quad * 8;
        v8s bf0 = *(const v8s*)kp;
        v8s bf1 = *(const v8s*)(kp + 32);
        #pragma unroll
        for (int mt = 0; mt < 2; ++mt) {
            v4f a = {};
            a = __builtin_amdgcn_mfma_f32_16x16x32_bf16(af[mt][0], bf0, a, 0, 0, 0);
            a = __builtin_amdgcn_mfma_f32_16x16x32_bf16(af[mt][1], bf1, a, 0, 0, 0);
            #pragma unroll
            for (int r = 0; r < 4; ++r) {
                int s = mt * 16 + quad * 4 + r;
                if (s < SS)
                    compat[(((long)b * HH + h) * SS + s) * NP + nt * 16 + l16] = a[r];
            }
        }
    }
}

// ---------------- K2b: mask + row softmax -> P bf16 (padded cols -> 0) ----------------
__global__ __launch_bounds__(256) void softmax_p(const float* __restrict__ compat,
                                                 const int* __restrict__ mask,
                                                 short* __restrict__ P) {
    int row = blockIdx.x * 4 + (threadIdx.x >> 6);  // row = (b*8+h)*20+s
    int lane = threadIdx.x & 63;
    int s = row % SS, bh = row / SS, b = bh / HH;
    const float* cr = compat + (long)row * NP;
    const int* mr = mask + ((long)b * SS + s) * NN;
    float x[16];
    float mx = NEGV;
    #pragma unroll
    for (int i = 0; i < 4; ++i) {
        int n0 = lane * 16 + i * 4;
        v4f v = *(const v4f*)(cr + n0);
        #pragma unroll
        for (int j = 0; j < 4; ++j) {
            int n = n0 + j;
            bool feas = (n < NN) && (mr[n < NN ? n : 0] != 0);
            x[i * 4 + j] = feas ? v[j] : NEGV;
            mx = fmaxf(mx, x[i * 4 + j]);
        }
    }
    for (int off = 32; off; off >>= 1) mx = fmaxf(mx, __shfl_xor(mx, off));
    float sum = 0.f;
    #pragma unroll
    for (int i = 0; i < 16; ++i) { x[i] = __expf(x[i] - mx); sum += x[i]; }
    for (int off = 32; off; off >>= 1) sum += __shfl_xor(sum, off);
    float inv = 1.0f / sum;
    short o[16];
    #pragma unroll
    for (int i = 0; i < 16; ++i) o[i] = f2bf(x[i] * inv);
    *(v8s*)(P + (long)row * NP + lane * 16) = *(v8s*)o;
    *(v8s*)(P + (long)row * NP + lane * 16 + 8) = *(v8s*)(o + 8);
}

// ---------------- K2c: heads[b][s][h*64+d] = P . V ----------------
__global__ __launch_bounds__(256) void pv_heads(const short* __restrict__ P,
                                                const short* __restrict__ kvl,
                                                float* __restrict__ heads) {
    int b = blockIdx.x, h = blockIdx.y;
    __shared__ __align__(16) short Vt[64 * 40];  // [d][n_local 32], pad 40
    int tid = threadIdx.x, wid = tid >> 6, lane = tid & 63, quad = lane >> 4, l16 = lane & 15;
    int mt = wid & 1, dt0 = (wid >> 1) * 2;
    int srow = mt * 16 + l16; if (srow > SS - 1) srow = SS - 1;  // clamp pad rows
    const short* prow = P + (((long)b * HH + h) * SS + srow) * NP + quad * 8;
    int nl = tid & 31, d0 = (tid >> 5) * 8;
    v4f acc[2] = {};
    for (int k0 = 0; k0 < NP; k0 += 32) {
        int n = k0 + nl;
        int ncl = n < NN ? n : NN - 1;
        const short* vp = kvl + ((long)b * NN + ncl) * 1536 + DD + h * 64 + d0;
        short vv[8];
        *(uint4*)vv = *(const uint4*)vp;
        __syncthreads();  // previous iter's frag reads done
        #pragma unroll
        for (int j = 0; j < 8; ++j) Vt[(d0 + j) * 40 + nl] = vv[j];
        __syncthreads();
        v8s afr = *(const v8s*)(prow + k0);
        #pragma unroll
        for (int i = 0; i < 2; ++i) {
            v8s bfr = *(const v8s*)(Vt + ((dt0 + i) * 16 + l16) * 40 + quad * 8);
            acc[i] = __builtin_amdgcn_mfma_f32_16x16x32_bf16(afr, bfr, acc[i], 0, 0, 0);
        }
    }
    #pragma unroll
    for (int i = 0; i < 2; ++i)
        #pragma unroll
        for (int r = 0; r < 4; ++r) {
            int s = mt * 16 + quad * 4 + r;
            if (s < SS)
                heads[((long)b * SS + s) * DD + h * 64 + (dt0 + i) * 16 + l16] = acc[i][r];
        }
}

// ---------------- K2d: glimpse[1280][512] = heads @ W_out ----------------
__global__ __launch_bounds__(256) void out_proj(const float* __restrict__ heads,
                                                const short* __restrict__ Wot,
                                                float* __restrict__ glimpse) {
    __shared__ __align__(16) short As[64 * 40], Bs[64 * 40];
    int tid = threadIdx.x;
    int m0 = blockIdx.x * 64, n0 = blockIdx.y * 64;
    int wid = tid >> 6, lane = tid & 63, quad = lane >> 4, l16 = lane & 15;
    int wm = wid & 1, wn = wid >> 1;
    int arow = tid >> 3, akol = (tid & 7) * 4;
    int brow = tid >> 2, bkol = (tid & 3) * 8;
    v4f acc[2][2] = {};
    for (int kk = 0; kk < 512; kk += 32) {
        #pragma unroll
        for (int p = 0; p < 2; ++p) {
            int r = arow + p * 32;
            v4f a = *(const v4f*)(heads + (long)(m0 + r) * 512 + kk + akol);
            short4 s4;
            s4.x = f2bf(a.x); s4.y = f2bf(a.y); s4.z = f2bf(a.z); s4.w = f2bf(a.w);
            *(short4*)(As + r * 40 + akol) = s4;
        }
        *(uint4*)(Bs + brow * 40 + bkol) =
            *(const uint4*)(Wot + (long)(n0 + brow) * 512 + kk + bkol);
        __syncthreads();
        #pragma unroll
        for (int i = 0; i < 2; ++i) {
            v8s af = *(const v8s*)(As + (wm * 32 + i * 16 + l16) * 40 + quad * 8);
            #pragma unroll
            for (int j = 0; j < 2; ++j) {
                v8s bf = *(const v8s*)(Bs + (wn * 32 + j * 16 + l16) * 40 + quad * 8);
                acc[i][j] = __builtin_amdgcn_mfma_f32_16x16x32_bf16(af, bf, acc[i][j], 0, 0, 0);
            }
        }
        __syncthreads();
    }
    #pragma unroll
    for (int i = 0; i < 2; ++i)
        #pragma unroll
        for (int j = 0; j < 2; ++j)
            #pragma unroll
            for (int r = 0; r < 4; ++r)
                glimpse[(long)(m0 + wm * 32 + i * 16 + quad * 4 + r) * 512 +
                        n0 + wn * 32 + j * 16 + l16] = acc[i][j][r];
}

// ---------------- K3a: logits[b][s][1024] = (glimpse . logit_k^T)/sqrt(512) ----------------
__global__ __launch_bounds__(256) void ptr_logits(const float* __restrict__ glimpse,
                                                  const short* __restrict__ kvl,
                                                  float* __restrict__ logits) {
    int b = blockIdx.x, nh = blockIdx.y;  // nh: n-half
    __shared__ __align__(16) short Gs[32 * 520];
    int tid = threadIdx.x;
    for (int i = tid; i < 32 * 512; i += 256) {
        int row = i >> 9, col = i & 511;
        float v = (row < SS) ? glimpse[((long)b * SS + row) * 512 + col] : 0.f;
        Gs[row * 520 + col] = f2bf(v);
    }
    __syncthreads();
    int wid = tid >> 6, lane = tid & 63, quad = lane >> 4, l16 = lane & 15;
    const float scale = 0.04419417382415922f;  // 1/sqrt(512)
    for (int tc = 0; tc < 2; ++tc) {
        v4f acc[2][4] = {};
        for (int k = 0; k < 16; ++k) {
            v8s af[2];
            #pragma unroll
            for (int m = 0; m < 2; ++m)
                af[m] = *(const v8s*)(Gs + (m * 16 + l16) * 520 + k * 32 + quad * 8);
            #pragma unroll
            for (int t = 0; t < 4; ++t) {
                int nt = nh * 32 + wid * 8 + tc * 4 + t;
                int n = nt * 16 + l16;
                int ncl = n < NN ? n : NN - 1;
                v8s bf = *(const v8s*)(kvl + ((long)b * NN + ncl) * 1536 + 1024 + k * 32 + quad * 8);
                #pragma unroll
                for (int m = 0; m < 2; ++m)
                    acc[m][t] = __builtin_amdgcn_mfma_f32_16x16x32_bf16(af[m], bf, acc[m][t], 0, 0, 0);
            }
        }
        #pragma unroll
        for (int m = 0; m < 2; ++m)
            #pragma unroll
            for (int t = 0; t < 4; ++t) {
                int nt = nh * 32 + wid * 8 + tc * 4 + t;
                #pragma unroll
                for (int r = 0; r < 4; ++r) {
                    int s = m * 16 + quad * 4 + r;
                    if (s < SS)
                        logits[((long)b * SS + s) * NP + nt * 16 + l16] = acc[m][t][r] * scale;
                }
            }
    }
}

// ---------------- K3b: tanh clip + mask + log_softmax + (s b) transpose ----------------
__global__ __launch_bounds__(256) void logsoftmax_out(const float* __restrict__ logits,
                                                      const int* __restrict__ mask,
                                                      float* __restrict__ out) {
    int row = blockIdx.x;  // b*20 + s
    int b = row / SS, s = row % SS;
    int tid = threadIdx.x;
    __shared__ float red[8];
    int n0 = tid * 4;
    v4f v = *(const v4f*)(logits + (long)row * NP + n0);
    const int* mr = mask + (long)row * NN;
    float x[4];
    float mx = NEGV;
    #pragma unroll
    for (int j = 0; j < 4; ++j) {
        int n = n0 + j;
        float t = 10.f * tanhf(v[j]);
        bool feas = (n < NN) && (mr[n < NN ? n : 0] != 0);
        x[j] = feas ? t : NEGV;
        mx = fmaxf(mx, x[j]);
    }
    for (int off = 32; off; off >>= 1) mx = fmaxf(mx, __shfl_xor(mx, off));
    int wid = tid >> 6, lane = tid & 63;
    if (lane == 0) red[wid] = mx;
    __syncthreads();
    mx = fmaxf(fmaxf(red[0], red[1]), fmaxf(red[2], red[3]));
    float sum = 0.f;
    #pragma unroll
    for (int j = 0; j < 4; ++j) sum += __expf(x[j] - mx);
    for (int off = 32; off; off >>= 1) sum += __shfl_xor(sum, off);
    __syncthreads();
    if (lane == 0) red[4 + wid] = sum;
    __syncthreads();
    sum = red[4] + red[5] + red[6] + red[7];
    float lse = mx + __logf(sum);
    float* orow = out + ((long)s * BB + b) * NN;
    #pragma unroll
    for (int j = 0; j < 4; ++j) {
        int n = n0 + j;
        if (n < NN) orow[n] = x[j] - lse;
    }
}

extern "C" void kernel_launch(void* const* d_in, const int* in_sizes, int n_in,
                              void* d_out, int out_size, void* d_ws, size_t ws_size,
                              hipStream_t stream) {
    const float* emb  = (const float*)d_in[0];
    const float* q    = (const float*)d_in[1];
    const int*   mask = (const int*)d_in[2];
    const float* Wkvl = (const float*)d_in[3];
    const float* Wout = (const float*)d_in[4];
    float* out = (float*)d_out;

    char* ws = (char*)d_ws;
    short* Wt      = (short*)ws; ws += (size_t)1536 * 512 * 2;
    short* Wot     = (short*)ws; ws += (size_t)512 * 512 * 2;
    short* embb    = (short*)ws; ws += (size_t)64000 * 512 * 2;
    short* kvl     = (short*)ws; ws += (size_t)64000 * 1536 * 2;
    float* compat  = (float*)ws; ws += (size_t)BB * HH * SS * NP * 4;
    short* P       = (short*)ws; ws += (size_t)BB * HH * SS * NP * 2;
    float* heads   = (float*)ws; ws += (size_t)BB * SS * DD * 4;
    float* glimpse = (float*)ws; ws += (size_t)BB * SS * DD * 4;
    float* logits  = (float*)ws; ws += (size_t)BB * SS * NP * 4;

    transpose_bf16<<<dim3(48, 16), 256, 0, stream>>>(Wkvl, Wt, 512, 1536);
    transpose_bf16<<<dim3(16, 16), 256, 0, stream>>>(Wout, Wot, 512, 512);
    cvt_bf16<<<dim3(16000), 256, 0, stream>>>(emb, embb, 64000 * 512 / 8);
    gemm_kvl<<<dim3(12, 500), 256, 0, stream>>>(embb, Wt, kvl);
    qk_compat<<<dim3(BB, HH), 256, 0, stream>>>(q, kvl, compat);
    softmax_p<<<dim3(BB * HH * SS / 4), 256, 0, stream>>>(compat, mask, P);
    pv_heads<<<dim3(BB, HH), 256, 0, stream>>>(P, kvl, heads);
    out_proj<<<dim3(20, 8), 256, 0, stream>>>(heads, Wot, glimpse);
    ptr_logits<<<dim3(BB, 2), 256, 0, stream>>>(glimpse, kvl, logits);
    logsoftmax_out<<<dim3(BB * SS), 256, 0, stream>>>(logits, mask, out);
}

// Round 2
// 493.000 us; speedup vs baseline: 1.1149x; 1.1149x over previous
//
#include <hip/hip_runtime.h>

#define BB 64
#define NN 1000
#define NP 1024
#define DD 512
#define HH 8
#define SS 20
#define NEGV -1e9f

typedef float v4f __attribute__((ext_vector_type(4)));
typedef short v8s __attribute__((ext_vector_type(8)));

static __device__ __forceinline__ short f2bf(float f) {
    unsigned u = __builtin_bit_cast(unsigned, f);
    u = (u + 0x7fffu + ((u >> 16) & 1u)) >> 16;
    return (short)u;
}

// async global->LDS, 16B per lane; lds dest must be wave-uniform base (+lane*16)
static __device__ __forceinline__ void gld16(const short* g, short* l) {
    __builtin_amdgcn_global_load_lds(
        (__attribute__((address_space(1))) void*)(g),
        (__attribute__((address_space(3))) void*)(l),
        16, 0, 0);
}

// ---------------- K0a: f32 [R][C] -> bf16 transposed [C][R] ----------------
__global__ void transpose_bf16(const float* __restrict__ src, short* __restrict__ dst,
                               int R, int C) {
    __shared__ float t[32][33];
    int c0 = blockIdx.x * 32, r0 = blockIdx.y * 32;
    int x = threadIdx.x & 31, y = threadIdx.x >> 5;  // y in 0..7
    for (int k = 0; k < 32; k += 8)
        t[y + k][x] = src[(long)(r0 + y + k) * C + c0 + x];
    __syncthreads();
    for (int k = 0; k < 32; k += 8)
        dst[(long)(c0 + y + k) * R + r0 + x] = f2bf(t[x][y + k]);
}

// ---------------- K0b: embeddings f32 -> bf16 ----------------
__global__ void cvt_bf16(const float* __restrict__ src, short* __restrict__ dst, int n8) {
    int i = blockIdx.x * 256 + threadIdx.x;
    if (i >= n8) return;
    long o = (long)i * 8;
    v4f a = *(const v4f*)(src + o);
    v4f b = *(const v4f*)(src + o + 4);
    short tmp[8] = {f2bf(a.x), f2bf(a.y), f2bf(a.z), f2bf(a.w),
                    f2bf(b.x), f2bf(b.y), f2bf(b.z), f2bf(b.w)};
    *(uint4*)(dst + o) = *(uint4*)tmp;
}

// ---------------- K1: kvl[64000][1536] = embb[64000][512] @ W_kvl (m97-style) ----------------
// Wt = W_kvl^T bf16 [1536][512]. 128x128 tile, BK=32, global_load_lds staging,
// unpadded k-contiguous LDS (required by global_load_lds lane ordering).
__global__ __launch_bounds__(256) void gemm_kvl(const short* __restrict__ embb,
                                                const short* __restrict__ Wt,
                                                short* __restrict__ kvl) {
    __shared__ __align__(16) short As[128 * 32];   // [m][k] 64B rows
    __shared__ __align__(16) short Bs[128 * 32];   // [n][k]
    __shared__ __align__(16) short rp[4 * 16 * 72];  // per-wave epilogue repack
    int tid = threadIdx.x;
    int n0 = blockIdx.x * 128, m0 = blockIdx.y * 128;  // n fastest: A-tile reuse
    int wid = tid >> 6, lane = tid & 63, quad = lane >> 4, l16 = lane & 15;
    int wm = wid & 1, wn = wid >> 1;
    v4f acc[4][4] = {};
    const short* Ag = embb + (long)m0 * 512;
    const short* Bg = Wt + (long)n0 * 512;
    // staging: chunk c = wid*128 + s*64 + lane; row = c>>2, kchunk = c&3
    int c0 = wid * 128 + lane;
    int row0 = c0 >> 2, kc0 = (c0 & 3) * 8;
    int c1 = c0 + 64;
    int row1 = c1 >> 2, kc1 = (c1 & 3) * 8;
    for (int kk = 0; kk < 512; kk += 32) {
        gld16(Ag + (long)row0 * 512 + kk + kc0, As + (wid * 128) * 8);
        gld16(Ag + (long)row1 * 512 + kk + kc1, As + (wid * 128 + 64) * 8);
        gld16(Bg + (long)row0 * 512 + kk + kc0, Bs + (wid * 128) * 8);
        gld16(Bg + (long)row1 * 512 + kk + kc1, Bs + (wid * 128 + 64) * 8);
        __syncthreads();
        v8s af[4], bf[4];
        #pragma unroll
        for (int i = 0; i < 4; ++i)
            af[i] = *(const v8s*)(As + (wm * 64 + i * 16 + l16) * 32 + quad * 8);
        #pragma unroll
        for (int j = 0; j < 4; ++j)
            bf[j] = *(const v8s*)(Bs + (wn * 64 + j * 16 + l16) * 32 + quad * 8);
        #pragma unroll
        for (int i = 0; i < 4; ++i)
            #pragma unroll
            for (int j = 0; j < 4; ++j)
                acc[i][j] = __builtin_amdgcn_mfma_f32_16x16x32_bf16(af[i], bf[j], acc[i][j], 0, 0, 0);
        __syncthreads();
    }
    // epilogue: wave-private repack (no barriers needed), vectorized stores
    short* r = rp + wid * (16 * 72);
    #pragma unroll
    for (int i = 0; i < 4; ++i) {
        #pragma unroll
        for (int j = 0; j < 4; ++j)
            #pragma unroll
            for (int rr = 0; rr < 4; ++rr)
                r[(quad * 4 + rr) * 72 + j * 16 + l16] = f2bf(acc[i][j][rr]);
        #pragma unroll
        for (int h = 0; h < 2; ++h) {
            int rowl = h * 8 + (lane >> 3);
            int colc = (lane & 7) * 8;
            v8s val = *(const v8s*)(r + rowl * 72 + colc);
            *(uint4*)(kvl + (long)(m0 + wm * 64 + i * 16 + rowl) * 1536 +
                      n0 + wn * 64 + colc) = *(uint4*)&val;
        }
    }
}

// ---------------- K2a: compat[(b*8+h)*20+s][1024] = (Q . K^T)/8 ----------------
__global__ __launch_bounds__(256) void qk_compat(const float* __restrict__ q,
                                                 const short* __restrict__ kvl,
                                                 float* __restrict__ compat) {
    int b = blockIdx.x, h = blockIdx.y, z = blockIdx.z;
    __shared__ __align__(16) short qs[32 * 72];
    int tid = threadIdx.x;
    for (int i = tid; i < 32 * 64; i += 256) {
        int row = i >> 6, col = i & 63;
        float v = (row < SS) ? q[((long)b * SS + row) * DD + h * 64 + col] * 0.125f : 0.f;
        qs[row * 72 + col] = f2bf(v);
    }
    __syncthreads();
    int wid = tid >> 6, lane = tid & 63, quad = lane >> 4, l16 = lane & 15;
    v8s af[2][2];
    #pragma unroll
    for (int mt = 0; mt < 2; ++mt)
        #pragma unroll
        for (int ks = 0; ks < 2; ++ks)
            af[mt][ks] = *(const v8s*)(qs + (mt * 16 + l16) * 72 + ks * 32 + quad * 8);
    for (int t = 0; t < 8; ++t) {
        int nt = z * 32 + wid * 8 + t;
        int n = nt * 16 + l16;
        int nc = n < NN ? n : NN - 1;
        const short* kp = kvl + ((long)b * NN + nc) * 1536 + h * 64 + quad * 8;
        v8s bf0 = *(const v8s*)kp;
        v8s bf1 = *(const v8s*)(kp + 32);
        #pragma unroll
        for (int mt = 0; mt < 2; ++mt) {
            v4f a = {};
            a = __builtin_amdgcn_mfma_f32_16x16x32_bf16(af[mt][0], bf0, a, 0, 0, 0);
            a = __builtin_amdgcn_mfma_f32_16x16x32_bf16(af[mt][1], bf1, a, 0, 0, 0);
            #pragma unroll
            for (int r = 0; r < 4; ++r) {
                int s = mt * 16 + quad * 4 + r;
                if (s < SS)
                    compat[(((long)b * HH + h) * SS + s) * NP + nt * 16 + l16] = a[r];
            }
        }
    }
}

// ---------------- K2b: mask + row softmax -> P bf16 (padded cols -> 0) ----------------
__global__ __launch_bounds__(256) void softmax_p(const float* __restrict__ compat,
                                                 const int* __restrict__ mask,
                                                 short* __restrict__ P) {
    int row = blockIdx.x * 4 + (threadIdx.x >> 6);  // row = (b*8+h)*20+s
    int lane = threadIdx.x & 63;
    int s = row % SS, bh = row / SS, b = bh / HH;
    const float* cr = compat + (long)row * NP;
    const int* mr = mask + ((long)b * SS + s) * NN;
    float x[16];
    float mx = NEGV;
    #pragma unroll
    for (int i = 0; i < 4; ++i) {
        int n0 = lane * 16 + i * 4;
        v4f v = *(const v4f*)(cr + n0);
        #pragma unroll
        for (int j = 0; j < 4; ++j) {
            int n = n0 + j;
            bool feas = (n < NN) && (mr[n < NN ? n : 0] != 0);
            x[i * 4 + j] = feas ? v[j] : NEGV;
            mx = fmaxf(mx, x[i * 4 + j]);
        }
    }
    for (int off = 32; off; off >>= 1) mx = fmaxf(mx, __shfl_xor(mx, off));
    float sum = 0.f;
    #pragma unroll
    for (int i = 0; i < 16; ++i) { x[i] = __expf(x[i] - mx); sum += x[i]; }
    for (int off = 32; off; off >>= 1) sum += __shfl_xor(sum, off);
    float inv = 1.0f / sum;
    short o[16];
    #pragma unroll
    for (int i = 0; i < 16; ++i) o[i] = f2bf(x[i] * inv);
    *(v8s*)(P + (long)row * NP + lane * 16) = *(v8s*)o;
    *(v8s*)(P + (long)row * NP + lane * 16 + 8) = *(v8s*)(o + 8);
}

// ---------------- K2c: heads[b][s][h*64+d] = P . V  (BK=64) ----------------
__global__ __launch_bounds__(256) void pv_heads(const short* __restrict__ P,
                                                const short* __restrict__ kvl,
                                                float* __restrict__ heads) {
    int b = blockIdx.x, h = blockIdx.y;
    __shared__ __align__(16) short Vt[64 * 72];  // [d][n_local 64], pad 72
    int tid = threadIdx.x, wid = tid >> 6, lane = tid & 63, quad = lane >> 4, l16 = lane & 15;
    int mt = wid & 1, dt0 = (wid >> 1) * 2;
    int srow = mt * 16 + l16; if (srow > SS - 1) srow = SS - 1;  // clamp pad rows
    const short* prow = P + (((long)b * HH + h) * SS + srow) * NP + quad * 8;
    int nl = tid & 63, ch = tid >> 6;  // staging: 64 n-rows, 2 chunks of 16B each
    v4f acc[2] = {};
    for (int k0 = 0; k0 < NP; k0 += 64) {
        int n = k0 + nl;
        int ncl = n < NN ? n : NN - 1;
        const short* vp = kvl + ((long)b * NN + ncl) * 1536 + DD + h * 64;
        short vv0[8], vv1[8];
        *(uint4*)vv0 = *(const uint4*)(vp + ch * 8);
        *(uint4*)vv1 = *(const uint4*)(vp + (ch + 4) * 8);
        __syncthreads();  // previous iter's frag reads done
        #pragma unroll
        for (int j = 0; j < 8; ++j) Vt[(ch * 8 + j) * 72 + nl] = vv0[j];
        #pragma unroll
        for (int j = 0; j < 8; ++j) Vt[((ch + 4) * 8 + j) * 72 + nl] = vv1[j];
        __syncthreads();
        #pragma unroll
        for (int ks = 0; ks < 2; ++ks) {
            v8s afr = *(const v8s*)(prow + k0 + ks * 32);
            #pragma unroll
            for (int i = 0; i < 2; ++i) {
                v8s bfr = *(const v8s*)(Vt + ((dt0 + i) * 16 + l16) * 72 + ks * 32 + quad * 8);
                acc[i] = __builtin_amdgcn_mfma_f32_16x16x32_bf16(afr, bfr, acc[i], 0, 0, 0);
            }
        }
    }
    #pragma unroll
    for (int i = 0; i < 2; ++i)
        #pragma unroll
        for (int r = 0; r < 4; ++r) {
            int s = mt * 16 + quad * 4 + r;
            if (s < SS)
                heads[((long)b * SS + s) * DD + h * 64 + (dt0 + i) * 16 + l16] = acc[i][r];
        }
}

// ---------------- K2d: glimpse[1280][512] = heads @ W_out ----------------
__global__ __launch_bounds__(256) void out_proj(const float* __restrict__ heads,
                                                const short* __restrict__ Wot,
                                                float* __restrict__ glimpse) {
    __shared__ __align__(16) short As[64 * 40], Bs[64 * 40];
    int tid = threadIdx.x;
    int m0 = blockIdx.x * 64, n0 = blockIdx.y * 64;
    int wid = tid >> 6, lane = tid & 63, quad = lane >> 4, l16 = lane & 15;
    int wm = wid & 1, wn = wid >> 1;
    int arow = tid >> 3, akol = (tid & 7) * 4;
    int brow = tid >> 2, bkol = (tid & 3) * 8;
    v4f acc[2][2] = {};
    for (int kk = 0; kk < 512; kk += 32) {
        #pragma unroll
        for (int p = 0; p < 2; ++p) {
            int r = arow + p * 32;
            v4f a = *(const v4f*)(heads + (long)(m0 + r) * 512 + kk + akol);
            short4 s4;
            s4.x = f2bf(a.x); s4.y = f2bf(a.y); s4.z = f2bf(a.z); s4.w = f2bf(a.w);
            *(short4*)(As + r * 40 + akol) = s4;
        }
        *(uint4*)(Bs + brow * 40 + bkol) =
            *(const uint4*)(Wot + (long)(n0 + brow) * 512 + kk + bkol);
        __syncthreads();
        #pragma unroll
        for (int i = 0; i < 2; ++i) {
            v8s af = *(const v8s*)(As + (wm * 32 + i * 16 + l16) * 40 + quad * 8);
            #pragma unroll
            for (int j = 0; j < 2; ++j) {
                v8s bf = *(const v8s*)(Bs + (wn * 32 + j * 16 + l16) * 40 + quad * 8);
                acc[i][j] = __builtin_amdgcn_mfma_f32_16x16x32_bf16(af, bf, acc[i][j], 0, 0, 0);
            }
        }
        __syncthreads();
    }
    #pragma unroll
    for (int i = 0; i < 2; ++i)
        #pragma unroll
        for (int j = 0; j < 2; ++j)
            #pragma unroll
            for (int r = 0; r < 4; ++r)
                glimpse[(long)(m0 + wm * 32 + i * 16 + quad * 4 + r) * 512 +
                        n0 + wn * 32 + j * 16 + l16] = acc[i][j][r];
}

// ---------------- K3a: logits[b][s][1024] = (glimpse . logit_k^T)/sqrt(512) ----------------
__global__ __launch_bounds__(256) void ptr_logits(const float* __restrict__ glimpse,
                                                  const short* __restrict__ kvl,
                                                  float* __restrict__ logits) {
    int b = blockIdx.x, g = blockIdx.y;  // g: n-group of 8 tiles
    __shared__ __align__(16) short Gs[32 * 520];
    int tid = threadIdx.x;
    #pragma unroll
    for (int it = 0; it < 16; ++it) {
        int e = it * 1024 + tid * 4;
        int row = e >> 9, col = e & 511;
        short4 s4;
        if (row < SS) {
            v4f a = *(const v4f*)(glimpse + ((long)b * SS + row) * 512 + col);
            s4.x = f2bf(a.x); s4.y = f2bf(a.y); s4.z = f2bf(a.z); s4.w = f2bf(a.w);
        } else {
            s4.x = s4.y = s4.z = s4.w = 0;
        }
        *(short4*)(Gs + row * 520 + col) = s4;
    }
    __syncthreads();
    int wid = tid >> 6, lane = tid & 63, quad = lane >> 4, l16 = lane & 15;
    const float scale = 0.04419417382415922f;  // 1/sqrt(512)
    #pragma unroll
    for (int tc = 0; tc < 2; ++tc) {
        int nt = g * 8 + wid * 2 + tc;
        int n = nt * 16 + l16;
        int ncl = n < NN ? n : NN - 1;
        const short* kp = kvl + ((long)b * NN + ncl) * 1536 + 1024 + quad * 8;
        v4f acc[2] = {};
        for (int k = 0; k < 16; ++k) {
            v8s bf = *(const v8s*)(kp + k * 32);
            #pragma unroll
            for (int m = 0; m < 2; ++m) {
                v8s af = *(const v8s*)(Gs + (m * 16 + l16) * 520 + k * 32 + quad * 8);
                acc[m] = __builtin_amdgcn_mfma_f32_16x16x32_bf16(af, bf, acc[m], 0, 0, 0);
            }
        }
        #pragma unroll
        for (int m = 0; m < 2; ++m)
            #pragma unroll
            for (int r = 0; r < 4; ++r) {
                int s = m * 16 + quad * 4 + r;
                if (s < SS)
                    logits[((long)b * SS + s) * NP + nt * 16 + l16] = acc[m][r] * scale;
            }
    }
}

// ---------------- K3b: tanh clip + mask + log_softmax + (s b) transpose ----------------
__global__ __launch_bounds__(256) void logsoftmax_out(const float* __restrict__ logits,
                                                      const int* __restrict__ mask,
                                                      float* __restrict__ out) {
    int row = blockIdx.x;  // b*20 + s
    int b = row / SS, s = row % SS;
    int tid = threadIdx.x;
    __shared__ float red[8];
    int n0 = tid * 4;
    v4f v = *(const v4f*)(logits + (long)row * NP + n0);
    const int* mr = mask + (long)row * NN;
    float x[4];
    float mx = NEGV;
    #pragma unroll
    for (int j = 0; j < 4; ++j) {
        int n = n0 + j;
        float t = 10.f * tanhf(v[j]);
        bool feas = (n < NN) && (mr[n < NN ? n : 0] != 0);
        x[j] = feas ? t : NEGV;
        mx = fmaxf(mx, x[j]);
    }
    for (int off = 32; off; off >>= 1) mx = fmaxf(mx, __shfl_xor(mx, off));
    int wid = tid >> 6, lane = tid & 63;
    if (lane == 0) red[wid] = mx;
    __syncthreads();
    mx = fmaxf(fmaxf(red[0], red[1]), fmaxf(red[2], red[3]));
    float sum = 0.f;
    #pragma unroll
    for (int j = 0; j < 4; ++j) sum += __expf(x[j] - mx);
    for (int off = 32; off; off >>= 1) sum += __shfl_xor(sum, off);
    __syncthreads();
    if (lane == 0) red[4 + wid] = sum;
    __syncthreads();
    sum = red[4] + red[5] + red[6] + red[7];
    float lse = mx + __logf(sum);
    float* orow = out + ((long)s * BB + b) * NN;
    #pragma unroll
    for (int j = 0; j < 4; ++j) {
        int n = n0 + j;
        if (n < NN) orow[n] = x[j] - lse;
    }
}

extern "C" void kernel_launch(void* const* d_in, const int* in_sizes, int n_in,
                              void* d_out, int out_size, void* d_ws, size_t ws_size,
                              hipStream_t stream) {
    const float* emb  = (const float*)d_in[0];
    const float* q    = (const float*)d_in[1];
    const int*   mask = (const int*)d_in[2];
    const float* Wkvl = (const float*)d_in[3];
    const float* Wout = (const float*)d_in[4];
    float* out = (float*)d_out;

    char* ws = (char*)d_ws;
    short* Wt      = (short*)ws; ws += (size_t)1536 * 512 * 2;
    short* Wot     = (short*)ws; ws += (size_t)512 * 512 * 2;
    short* embb    = (short*)ws; ws += (size_t)64000 * 512 * 2;
    short* kvl     = (short*)ws; ws += (size_t)64000 * 1536 * 2;
    float* compat  = (float*)ws; ws += (size_t)BB * HH * SS * NP * 4;
    short* P       = (short*)ws; ws += (size_t)BB * HH * SS * NP * 2;
    float* heads   = (float*)ws; ws += (size_t)BB * SS * DD * 4;
    float* glimpse = (float*)ws; ws += (size_t)BB * SS * DD * 4;
    float* logits  = (float*)ws; ws += (size_t)BB * SS * NP * 4;

    transpose_bf16<<<dim3(48, 16), 256, 0, stream>>>(Wkvl, Wt, 512, 1536);
    transpose_bf16<<<dim3(16, 16), 256, 0, stream>>>(Wout, Wot, 512, 512);
    cvt_bf16<<<dim3(16000), 256, 0, stream>>>(emb, embb, 64000 * 512 / 8);
    gemm_kvl<<<dim3(12, 500), 256, 0, stream>>>(embb, Wt, kvl);
    qk_compat<<<dim3(BB, HH, 2), 256, 0, stream>>>(q, kvl, compat);
    softmax_p<<<dim3(BB * HH * SS / 4), 256, 0, stream>>>(compat, mask, P);
    pv_heads<<<dim3(BB, HH), 256, 0, stream>>>(P, kvl, heads);
    out_proj<<<dim3(20, 8), 256, 0, stream>>>(heads, Wot, glimpse);
    ptr_logits<<<dim3(BB, 8), 256, 0, stream>>>(glimpse, kvl, logits);
    logsoftmax_out<<<dim3(BB * SS), 256, 0, stream>>>(logits, mask, out);
}

// Round 3
// 407.491 us; speedup vs baseline: 1.3488x; 1.2098x over previous
//
#include <hip/hip_runtime.h>

#define BB 64
#define NN 1000
#define NP 1024
#define DD 512
#define HH 8
#define SS 20
#define NEGV -1e9f

typedef float v4f __attribute__((ext_vector_type(4)));
typedef short v8s __attribute__((ext_vector_type(8)));
typedef int   v8i __attribute__((ext_vector_type(8)));
typedef int   v4i __attribute__((ext_vector_type(4)));

static __device__ __forceinline__ short f2bf(float f) {
    unsigned u = __builtin_bit_cast(unsigned, f);
    u = (u + 0x7fffu + ((u >> 16) & 1u)) >> 16;
    return (short)u;
}
static __device__ __forceinline__ float bf2f(short s) {
    unsigned u = ((unsigned)(unsigned short)s) << 16;
    return __builtin_bit_cast(float, u);
}

// async global->LDS, 16B per lane; lds dest = wave-uniform base + lane*16
static __device__ __forceinline__ void gld16(const void* g, void* l) {
    __builtin_amdgcn_global_load_lds(
        (const __attribute__((address_space(1))) void*)(g),
        (__attribute__((address_space(3))) void*)(l),
        16, 0, 0);
}

// ---------------- K0a: W_out f32 [R][C] -> bf16 transposed [C][R] ----------------
__global__ void transpose_bf16(const float* __restrict__ src, short* __restrict__ dst,
                               int R, int C) {
    __shared__ float t[32][33];
    int c0 = blockIdx.x * 32, r0 = blockIdx.y * 32;
    int x = threadIdx.x & 31, y = threadIdx.x >> 5;
    for (int k = 0; k < 32; k += 8)
        t[y + k][x] = src[(long)(r0 + y + k) * C + c0 + x];
    __syncthreads();
    for (int k = 0; k < 32; k += 8)
        dst[(long)(c0 + y + k) * R + r0 + x] = f2bf(t[x][y + k]);
}

// ---------------- K0b: W_kvl f32 [R][C] -> fp8 e4m3 transposed [C][R] ----------------
__global__ void transpose_fp8(const float* __restrict__ src, unsigned char* __restrict__ dst,
                              int R, int C) {
    __shared__ float t[32][33];
    int c0 = blockIdx.x * 32, r0 = blockIdx.y * 32;
    int x = threadIdx.x & 31, y = threadIdx.x >> 5;
    for (int k = 0; k < 32; k += 8)
        t[y + k][x] = src[(long)(r0 + y + k) * C + c0 + x];
    __syncthreads();
    for (int k = 0; k < 32; k += 8) {
        int p = __builtin_amdgcn_cvt_pk_fp8_f32(t[x][y + k], 0.f, 0, false);
        dst[(long)(c0 + y + k) * R + r0 + x] = (unsigned char)(p & 0xff);
    }
}

// ---------------- K0c: embeddings f32 -> fp8 e4m3 ----------------
__global__ void cvt_fp8(const float* __restrict__ src, int* __restrict__ dst, int n8) {
    int i = blockIdx.x * 256 + threadIdx.x;
    if (i >= n8) return;
    long o = (long)i * 8;
    v4f a = *(const v4f*)(src + o);
    v4f b = *(const v4f*)(src + o + 4);
    int lo = __builtin_amdgcn_cvt_pk_fp8_f32(a.x, a.y, 0, false);
    lo = __builtin_amdgcn_cvt_pk_fp8_f32(a.z, a.w, lo, true);
    int hi = __builtin_amdgcn_cvt_pk_fp8_f32(b.x, b.y, 0, false);
    hi = __builtin_amdgcn_cvt_pk_fp8_f32(b.z, b.w, hi, true);
    int2 r; r.x = lo; r.y = hi;
    *(int2*)(dst + i * 2) = r;
}

// ---------------- K1: kvl[64000][1536] = emb8 @ Wt8  (MX-fp8, unit scales) ----------------
// 128x128 tile, BK=128, global_load_lds staging with XOR chunk swizzle.
__global__ __launch_bounds__(256) void gemm_kvl(const unsigned char* __restrict__ emb8,
                                                const unsigned char* __restrict__ Wt8,
                                                short* __restrict__ kvl) {
    __shared__ __align__(16) unsigned char As[128 * 128];  // [m][k], chunk c holds data chunk c^(m&7)
    __shared__ __align__(16) unsigned char Bs[128 * 128];  // [n][k]
    __shared__ __align__(16) short rp[4 * 16 * 72];
    int tid = threadIdx.x;
    int n0 = blockIdx.x * 128, m0 = blockIdx.y * 128;  // n fastest: A-tile reuse
    int wid = tid >> 6, lane = tid & 63, quad = lane >> 4, l16 = lane & 15;
    int wm = wid & 1, wn = wid >> 1;
    v4f acc[4][4] = {};
    const unsigned char* Ag = emb8 + (long)m0 * 512;
    const unsigned char* Bg = Wt8 + (long)n0 * 512;
    int rsub = lane >> 3;                 // row within 8-row gld16 group
    int kc = ((lane & 7) ^ rsub) * 16;    // swizzled source chunk
    for (int kk = 0; kk < 512; kk += 128) {
        #pragma unroll
        for (int p = 0; p < 4; ++p) {
            int rl = wid * 32 + p * 8;
            gld16(Ag + (long)(rl + rsub) * 512 + kk + kc, As + rl * 128);
            gld16(Bg + (long)(rl + rsub) * 512 + kk + kc, Bs + rl * 128);
        }
        __syncthreads();
        v8i af[4], bf[4];
        #pragma unroll
        for (int i = 0; i < 4; ++i) {
            int m = wm * 64 + i * 16 + l16;
            int c0 = (quad * 2) ^ (m & 7), c1 = (quad * 2 + 1) ^ (m & 7);
            v4i lo = *(const v4i*)(As + m * 128 + c0 * 16);
            v4i hi = *(const v4i*)(As + m * 128 + c1 * 16);
            af[i] = __builtin_shufflevector(lo, hi, 0, 1, 2, 3, 4, 5, 6, 7);
        }
        #pragma unroll
        for (int j = 0; j < 4; ++j) {
            int n = wn * 64 + j * 16 + l16;
            int c0 = (quad * 2) ^ (n & 7), c1 = (quad * 2 + 1) ^ (n & 7);
            v4i lo = *(const v4i*)(Bs + n * 128 + c0 * 16);
            v4i hi = *(const v4i*)(Bs + n * 128 + c1 * 16);
            bf[j] = __builtin_shufflevector(lo, hi, 0, 1, 2, 3, 4, 5, 6, 7);
        }
        #pragma unroll
        for (int i = 0; i < 4; ++i)
            #pragma unroll
            for (int j = 0; j < 4; ++j)
                acc[i][j] = __builtin_amdgcn_mfma_scale_f32_16x16x128_f8f6f4(
                    af[i], bf[j], acc[i][j], 0, 0, 0, 0x7f7f7f7f, 0, 0x7f7f7f7f);
        __syncthreads();
    }
    // epilogue: wave-private LDS repack, coalesced vector stores (R2-verified)
    short* r = rp + wid * (16 * 72);
    #pragma unroll
    for (int i = 0; i < 4; ++i) {
        #pragma unroll
        for (int j = 0; j < 4; ++j)
            #pragma unroll
            for (int rr = 0; rr < 4; ++rr)
                r[(quad * 4 + rr) * 72 + j * 16 + l16] = f2bf(acc[i][j][rr]);
        #pragma unroll
        for (int h = 0; h < 2; ++h) {
            int rowl = h * 8 + (lane >> 3);
            int colc = (lane & 7) * 8;
            v8s val = *(const v8s*)(r + rowl * 72 + colc);
            *(uint4*)(kvl + (long)(m0 + wm * 64 + i * 16 + rowl) * 1536 +
                      n0 + wn * 64 + colc) = *(uint4*)&val;
        }
    }
}

// ---------------- K2: V-part of kvl -> Vt[bh][d(64)][n(1024)] bf16 ----------------
__global__ void transpose_v(const short* __restrict__ kvl, short* __restrict__ Vt) {
    int bh = blockIdx.x, b = bh >> 3, h = bh & 7;
    int ny = blockIdx.y, dz = blockIdx.z;
    __shared__ short T[32][33];
    int x = threadIdx.x & 31, y = threadIdx.x >> 5;
    for (int k = 0; k < 32; k += 8) {
        int n = ny * 32 + y + k;
        T[y + k][x] = (n < NN)
            ? kvl[((long)b * NN + n) * 1536 + DD + h * 64 + dz * 32 + x] : (short)0;
    }
    __syncthreads();
    for (int k = 0; k < 32; k += 8)
        Vt[((long)bh * 64 + dz * 32 + y + k) * NP + ny * 32 + x] = T[x][y + k];
}

// ---------------- K3: fused QK^T -> masked softmax -> PV  (one block per b,h) ----------------
#define CST 1048  // cmp row stride (shorts): mult of 8 (16B align), 524 words %32=12 -> conflict-free frags
__global__ __launch_bounds__(256) void attn_fused(const float* __restrict__ q,
                                                  const short* __restrict__ kvl,
                                                  const short* __restrict__ Vt,
                                                  const int* __restrict__ mask,
                                                  float* __restrict__ heads) {
    int b = blockIdx.x, h = blockIdx.y;
    __shared__ __align__(16) short qs[32 * 72];
    __shared__ __align__(16) short cmp[32 * CST];  // compat bf16 -> P bf16 in place
    int tid = threadIdx.x, wid = tid >> 6, lane = tid & 63, quad = lane >> 4, l16 = lane & 15;
    for (int i = tid; i < 32 * 64; i += 256) {
        int row = i >> 6, col = i & 63;
        float v = (row < SS) ? q[((long)b * SS + row) * DD + h * 64 + col] * 0.125f : 0.f;
        qs[row * 72 + col] = f2bf(v);
    }
    __syncthreads();
    // --- QK^T ---
    v8s af[2][2];
    #pragma unroll
    for (int mt = 0; mt < 2; ++mt)
        #pragma unroll
        for (int ks = 0; ks < 2; ++ks)
            af[mt][ks] = *(const v8s*)(qs + (mt * 16 + l16) * 72 + ks * 32 + quad * 8);
    for (int t = 0; t < 16; ++t) {
        int nt = wid * 16 + t;
        int n = nt * 16 + l16;
        int nc = n < NN ? n : NN - 1;
        const short* kp = kvl + ((long)b * NN + nc) * 1536 + h * 64 + quad * 8;
        v8s bf0 = *(const v8s*)kp;
        v8s bf1 = *(const v8s*)(kp + 32);
        #pragma unroll
        for (int mt = 0; mt < 2; ++mt) {
            v4f a = {};
            a = __builtin_amdgcn_mfma_f32_16x16x32_bf16(af[mt][0], bf0, a, 0, 0, 0);
            a = __builtin_amdgcn_mfma_f32_16x16x32_bf16(af[mt][1], bf1, a, 0, 0, 0);
            #pragma unroll
            for (int r = 0; r < 4; ++r) {
                int s = mt * 16 + quad * 4 + r;
                if (s < SS) cmp[s * CST + nt * 16 + l16] = f2bf(a[r]);
            }
        }
    }
    __syncthreads();
    // --- masked softmax, P (bf16) written in place ---
    for (int s = wid; s < SS; s += 4) {
        const int* mr = mask + ((long)b * SS + s) * NN;
        float x[16];
        float mx = NEGV;
        #pragma unroll
        for (int i = 0; i < 16; ++i) {
            int n = lane + 64 * i;
            float v = bf2f(cmp[s * CST + n]);
            bool feas = (n < NN) && (mr[n < NN ? n : 0] != 0);
            x[i] = feas ? v : NEGV;
            mx = fmaxf(mx, x[i]);
        }
        for (int off = 32; off; off >>= 1) mx = fmaxf(mx, __shfl_xor(mx, off));
        float sum = 0.f;
        #pragma unroll
        for (int i = 0; i < 16; ++i) { x[i] = __expf(x[i] - mx); sum += x[i]; }
        for (int off = 32; off; off >>= 1) sum += __shfl_xor(sum, off);
        float inv = 1.0f / sum;
        #pragma unroll
        for (int i = 0; i < 16; ++i) cmp[s * CST + lane + 64 * i] = f2bf(x[i] * inv);
    }
    __syncthreads();
    // --- PV: A = P rows (LDS), B = Vt (global, k-contiguous) ---
    int mt = wid & 1, dt0 = (wid >> 1) * 2;
    const short* vb = Vt + ((long)(b * HH + h)) * 64 * NP;
    v4f acc[2] = {};
    for (int k0 = 0; k0 < NP; k0 += 32) {
        v8s afr = *(const v8s*)(cmp + (mt * 16 + l16) * CST + k0 + quad * 8);
        #pragma unroll
        for (int i = 0; i < 2; ++i) {
            v8s bfr = *(const v8s*)(vb + (long)((dt0 + i) * 16 + l16) * NP + k0 + quad * 8);
            acc[i] = __builtin_amdgcn_mfma_f32_16x16x32_bf16(afr, bfr, acc[i], 0, 0, 0);
        }
    }
    #pragma unroll
    for (int i = 0; i < 2; ++i)
        #pragma unroll
        for (int r = 0; r < 4; ++r) {
            int s = mt * 16 + quad * 4 + r;
            if (s < SS)
                heads[((long)b * SS + s) * DD + h * 64 + (dt0 + i) * 16 + l16] = acc[i][r];
        }
}

// ---------------- K4: glimpse[1280][512] = heads @ W_out ----------------
__global__ __launch_bounds__(256) void out_proj(const float* __restrict__ heads,
                                                const short* __restrict__ Wot,
                                                float* __restrict__ glimpse) {
    __shared__ __align__(16) short As[64 * 40], Bs[64 * 40];
    int tid = threadIdx.x;
    int m0 = blockIdx.x * 64, n0 = blockIdx.y * 64;
    int wid = tid >> 6, lane = tid & 63, quad = lane >> 4, l16 = lane & 15;
    int wm = wid & 1, wn = wid >> 1;
    int arow = tid >> 3, akol = (tid & 7) * 4;
    int brow = tid >> 2, bkol = (tid & 3) * 8;
    v4f acc[2][2] = {};
    for (int kk = 0; kk < 512; kk += 32) {
        #pragma unroll
        for (int p = 0; p < 2; ++p) {
            int r = arow + p * 32;
            v4f a = *(const v4f*)(heads + (long)(m0 + r) * 512 + kk + akol);
            short4 s4;
            s4.x = f2bf(a.x); s4.y = f2bf(a.y); s4.z = f2bf(a.z); s4.w = f2bf(a.w);
            *(short4*)(As + r * 40 + akol) = s4;
        }
        *(uint4*)(Bs + brow * 40 + bkol) =
            *(const uint4*)(Wot + (long)(n0 + brow) * 512 + kk + bkol);
        __syncthreads();
        #pragma unroll
        for (int i = 0; i < 2; ++i) {
            v8s af = *(const v8s*)(As + (wm * 32 + i * 16 + l16) * 40 + quad * 8);
            #pragma unroll
            for (int j = 0; j < 2; ++j) {
                v8s bf = *(const v8s*)(Bs + (wn * 32 + j * 16 + l16) * 40 + quad * 8);
                acc[i][j] = __builtin_amdgcn_mfma_f32_16x16x32_bf16(af, bf, acc[i][j], 0, 0, 0);
            }
        }
        __syncthreads();
    }
    #pragma unroll
    for (int i = 0; i < 2; ++i)
        #pragma unroll
        for (int j = 0; j < 2; ++j)
            #pragma unroll
            for (int r = 0; r < 4; ++r)
                glimpse[(long)(m0 + wm * 32 + i * 16 + quad * 4 + r) * 512 +
                        n0 + wn * 32 + j * 16 + l16] = acc[i][j][r];
}

// ---------------- K5: logits[b][s][1024] = (glimpse . logit_k^T)/sqrt(512) ----------------
__global__ __launch_bounds__(256) void ptr_logits(const float* __restrict__ glimpse,
                                                  const short* __restrict__ kvl,
                                                  float* __restrict__ logits) {
    int b = blockIdx.x, g = blockIdx.y;
    __shared__ __align__(16) short Gs[32 * 520];
    int tid = threadIdx.x;
    #pragma unroll
    for (int it = 0; it < 16; ++it) {
        int e = it * 1024 + tid * 4;
        int row = e >> 9, col = e & 511;
        short4 s4;
        if (row < SS) {
            v4f a = *(const v4f*)(glimpse + ((long)b * SS + row) * 512 + col);
            s4.x = f2bf(a.x); s4.y = f2bf(a.y); s4.z = f2bf(a.z); s4.w = f2bf(a.w);
        } else {
            s4.x = s4.y = s4.z = s4.w = 0;
        }
        *(short4*)(Gs + row * 520 + col) = s4;
    }
    __syncthreads();
    int wid = tid >> 6, lane = tid & 63, quad = lane >> 4, l16 = lane & 15;
    const float scale = 0.04419417382415922f;  // 1/sqrt(512)
    #pragma unroll
    for (int tc = 0; tc < 2; ++tc) {
        int nt = g * 8 + wid * 2 + tc;
        int n = nt * 16 + l16;
        int ncl = n < NN ? n : NN - 1;
        const short* kp = kvl + ((long)b * NN + ncl) * 1536 + 1024 + quad * 8;
        v4f acc[2] = {};
        for (int k = 0; k < 16; ++k) {
            v8s bf = *(const v8s*)(kp + k * 32);
            #pragma unroll
            for (int m = 0; m < 2; ++m) {
                v8s af = *(const v8s*)(Gs + (m * 16 + l16) * 520 + k * 32 + quad * 8);
                acc[m] = __builtin_amdgcn_mfma_f32_16x16x32_bf16(af, bf, acc[m], 0, 0, 0);
            }
        }
        #pragma unroll
        for (int m = 0; m < 2; ++m)
            #pragma unroll
            for (int r = 0; r < 4; ++r) {
                int s = m * 16 + quad * 4 + r;
                if (s < SS)
                    logits[((long)b * SS + s) * NP + nt * 16 + l16] = acc[m][r] * scale;
            }
    }
}

// ---------------- K6: tanh clip + mask + log_softmax + (s b) transpose ----------------
__global__ __launch_bounds__(256) void logsoftmax_out(const float* __restrict__ logits,
                                                      const int* __restrict__ mask,
                                                      float* __restrict__ out) {
    int row = blockIdx.x;  // b*20 + s
    int b = row / SS, s = row % SS;
    int tid = threadIdx.x;
    __shared__ float red[8];
    int n0 = tid * 4;
    v4f v = *(const v4f*)(logits + (long)row * NP + n0);
    const int* mr = mask + (long)row * NN;
    float x[4];
    float mx = NEGV;
    #pragma unroll
    for (int j = 0; j < 4; ++j) {
        int n = n0 + j;
        float t = 10.f * tanhf(v[j]);
        bool feas = (n < NN) && (mr[n < NN ? n : 0] != 0);
        x[j] = feas ? t : NEGV;
        mx = fmaxf(mx, x[j]);
    }
    for (int off = 32; off; off >>= 1) mx = fmaxf(mx, __shfl_xor(mx, off));
    int wid = tid >> 6, lane = tid & 63;
    if (lane == 0) red[wid] = mx;
    __syncthreads();
    mx = fmaxf(fmaxf(red[0], red[1]), fmaxf(red[2], red[3]));
    float sum = 0.f;
    #pragma unroll
    for (int j = 0; j < 4; ++j) sum += __expf(x[j] - mx);
    for (int off = 32; off; off >>= 1) sum += __shfl_xor(sum, off);
    __syncthreads();
    if (lane == 0) red[4 + wid] = sum;
    __syncthreads();
    sum = red[4] + red[5] + red[6] + red[7];
    float lse = mx + __logf(sum);
    float* orow = out + ((long)s * BB + b) * NN;
    #pragma unroll
    for (int j = 0; j < 4; ++j) {
        int n = n0 + j;
        if (n < NN) orow[n] = x[j] - lse;
    }
}

extern "C" void kernel_launch(void* const* d_in, const int* in_sizes, int n_in,
                              void* d_out, int out_size, void* d_ws, size_t ws_size,
                              hipStream_t stream) {
    const float* emb  = (const float*)d_in[0];
    const float* q    = (const float*)d_in[1];
    const int*   mask = (const int*)d_in[2];
    const float* Wkvl = (const float*)d_in[3];
    const float* Wout = (const float*)d_in[4];
    float* out = (float*)d_out;

    char* ws = (char*)d_ws;
    short* kvl     = (short*)ws; ws += (size_t)64000 * 1536 * 2;
    short* Vt      = (short*)ws; ws += (size_t)512 * 64 * NP * 2;
    short* Wot     = (short*)ws; ws += (size_t)512 * 512 * 2;
    float* heads   = (float*)ws; ws += (size_t)BB * SS * DD * 4;
    float* glimpse = (float*)ws; ws += (size_t)BB * SS * DD * 4;
    float* logits  = (float*)ws; ws += (size_t)BB * SS * NP * 4;
    unsigned char* Wt8  = (unsigned char*)ws; ws += (size_t)1536 * 512;
    unsigned char* emb8 = (unsigned char*)ws; ws += (size_t)64000 * 512;

    transpose_fp8<<<dim3(48, 16), 256, 0, stream>>>(Wkvl, Wt8, 512, 1536);
    transpose_bf16<<<dim3(16, 16), 256, 0, stream>>>(Wout, Wot, 512, 512);
    cvt_fp8<<<dim3(16000), 256, 0, stream>>>(emb, (int*)emb8, 64000 * 512 / 8);
    gemm_kvl<<<dim3(12, 500), 256, 0, stream>>>(emb8, Wt8, kvl);
    transpose_v<<<dim3(512, 32, 2), 256, 0, stream>>>(kvl, Vt);
    attn_fused<<<dim3(BB, HH), 256, 0, stream>>>(q, kvl, Vt, mask, heads);
    out_proj<<<dim3(20, 8), 256, 0, stream>>>(heads, Wot, glimpse);
    ptr_logits<<<dim3(BB, 8), 256, 0, stream>>>(glimpse, kvl, logits);
    logsoftmax_out<<<dim3(BB * SS), 256, 0, stream>>>(logits, mask, out);
}

// Round 4
// 360.021 us; speedup vs baseline: 1.5267x; 1.1319x over previous
//
#include <hip/hip_runtime.h>

#define BB 64
#define NN 1000
#define NP 1024
#define DD 512
#define HH 8
#define SS 20
#define NEGV -1e9f

typedef float v4f __attribute__((ext_vector_type(4)));
typedef short v8s __attribute__((ext_vector_type(8)));
typedef int   v8i __attribute__((ext_vector_type(8)));
typedef int   v4i __attribute__((ext_vector_type(4)));
typedef unsigned char uchar;
typedef unsigned long long ulong_t;

static __device__ __forceinline__ short f2bf(float f) {
    unsigned u = __builtin_bit_cast(unsigned, f);
    u = (u + 0x7fffu + ((u >> 16) & 1u)) >> 16;
    return (short)u;
}
static __device__ __forceinline__ float bf2f(short s) {
    unsigned u = ((unsigned)(unsigned short)s) << 16;
    return __builtin_bit_cast(float, u);
}
static __device__ __forceinline__ uchar f2fp8(float f) {
    return (uchar)(__builtin_amdgcn_cvt_pk_fp8_f32(f, 0.f, 0, false) & 0xff);
}

// async global->LDS, 16B per lane; lds dest = wave-uniform base + lane*16
static __device__ __forceinline__ void gld16(const void* g, void* l) {
    __builtin_amdgcn_global_load_lds(
        (const __attribute__((address_space(1))) void*)(g),
        (__attribute__((address_space(3))) void*)(l),
        16, 0, 0);
}

// ---------------- K0a: W_out f32 [R][C] -> bf16 transposed [C][R] ----------------
__global__ void transpose_bf16(const float* __restrict__ src, short* __restrict__ dst,
                               int R, int C) {
    __shared__ float t[32][33];
    int c0 = blockIdx.x * 32, r0 = blockIdx.y * 32;
    int x = threadIdx.x & 31, y = threadIdx.x >> 5;
    for (int k = 0; k < 32; k += 8)
        t[y + k][x] = src[(long)(r0 + y + k) * C + c0 + x];
    __syncthreads();
    for (int k = 0; k < 32; k += 8)
        dst[(long)(c0 + y + k) * R + r0 + x] = f2bf(t[x][y + k]);
}

// ---------------- K0b: W_kvl f32 [R][C] -> fp8 e4m3 transposed [C][R] ----------------
__global__ void transpose_fp8(const float* __restrict__ src, uchar* __restrict__ dst,
                              int R, int C) {
    __shared__ float t[32][33];
    int c0 = blockIdx.x * 32, r0 = blockIdx.y * 32;
    int x = threadIdx.x & 31, y = threadIdx.x >> 5;
    for (int k = 0; k < 32; k += 8)
        t[y + k][x] = src[(long)(r0 + y + k) * C + c0 + x];
    __syncthreads();
    for (int k = 0; k < 32; k += 8)
        dst[(long)(c0 + y + k) * R + r0 + x] = f2fp8(t[x][y + k]);
}

// ---------------- K0c: embeddings f32 -> fp8 e4m3 ----------------
__global__ void cvt_fp8(const float* __restrict__ src, int* __restrict__ dst, int n8) {
    int i = blockIdx.x * 256 + threadIdx.x;
    if (i >= n8) return;
    long o = (long)i * 8;
    v4f a = *(const v4f*)(src + o);
    v4f b = *(const v4f*)(src + o + 4);
    int lo = __builtin_amdgcn_cvt_pk_fp8_f32(a.x, a.y, 0, false);
    lo = __builtin_amdgcn_cvt_pk_fp8_f32(a.z, a.w, lo, true);
    int hi = __builtin_amdgcn_cvt_pk_fp8_f32(b.x, b.y, 0, false);
    hi = __builtin_amdgcn_cvt_pk_fp8_f32(b.z, b.w, hi, true);
    int2 r; r.x = lo; r.y = hi;
    *(int2*)(dst + i * 2) = r;
}

// ---------------- K1: kvl8[64000][1536] = emb8 @ Wt8  (MX-fp8, unit scales) ----------------
// 128x128 tile, BK=128, gld16 staging w/ XOR swizzle, fp8 OUTPUT, XCD-aware id swizzle.
__global__ __launch_bounds__(256) void gemm_kvl(const uchar* __restrict__ emb8,
                                                const uchar* __restrict__ Wt8,
                                                uchar* __restrict__ kvl8) {
    __shared__ __align__(16) uchar As[128 * 128];
    __shared__ __align__(16) uchar Bs[128 * 128];
    __shared__ __align__(16) short rp[4 * 16 * 72];
    int tid = threadIdx.x;
    // XCD swizzle: groups of 96 = 8 m-rows x 12 n; id%8 picks m-row so all 12
    // n-blocks of one A-row land on the same XCD (round-robin dispatch).
    int id = blockIdx.x;
    int m_idx, n_idx;
    if (id < 5952) { int g = id / 96, r = id % 96; m_idx = g * 8 + (r & 7); n_idx = r >> 3; }
    else { int t = id - 5952; m_idx = 496 + (t & 3); n_idx = t >> 2; }
    int n0 = n_idx * 128, m0 = m_idx * 128;
    int wid = tid >> 6, lane = tid & 63, quad = lane >> 4, l16 = lane & 15;
    int wm = wid & 1, wn = wid >> 1;
    v4f acc[4][4] = {};
    const uchar* Ag = emb8 + (long)m0 * 512;
    const uchar* Bg = Wt8 + (long)n0 * 512;
    int rsub = lane >> 3;
    int kc = ((lane & 7) ^ rsub) * 16;
    for (int kk = 0; kk < 512; kk += 128) {
        #pragma unroll
        for (int p = 0; p < 4; ++p) {
            int rl = wid * 32 + p * 8;
            gld16(Ag + (long)(rl + rsub) * 512 + kk + kc, As + rl * 128);
            gld16(Bg + (long)(rl + rsub) * 512 + kk + kc, Bs + rl * 128);
        }
        __syncthreads();
        v8i af[4], bf[4];
        #pragma unroll
        for (int i = 0; i < 4; ++i) {
            int m = wm * 64 + i * 16 + l16;
            int c0 = (quad * 2) ^ (m & 7), c1 = (quad * 2 + 1) ^ (m & 7);
            v4i lo = *(const v4i*)(As + m * 128 + c0 * 16);
            v4i hi = *(const v4i*)(As + m * 128 + c1 * 16);
            af[i] = __builtin_shufflevector(lo, hi, 0, 1, 2, 3, 4, 5, 6, 7);
        }
        #pragma unroll
        for (int j = 0; j < 4; ++j) {
            int n = wn * 64 + j * 16 + l16;
            int c0 = (quad * 2) ^ (n & 7), c1 = (quad * 2 + 1) ^ (n & 7);
            v4i lo = *(const v4i*)(Bs + n * 128 + c0 * 16);
            v4i hi = *(const v4i*)(Bs + n * 128 + c1 * 16);
            bf[j] = __builtin_shufflevector(lo, hi, 0, 1, 2, 3, 4, 5, 6, 7);
        }
        #pragma unroll
        for (int i = 0; i < 4; ++i)
            #pragma unroll
            for (int j = 0; j < 4; ++j)
                acc[i][j] = __builtin_amdgcn_mfma_scale_f32_16x16x128_f8f6f4(
                    af[i], bf[j], acc[i][j], 0, 0, 0, 0x7f7f7f7f, 0, 0x7f7f7f7f);
        __syncthreads();
    }
    // epilogue: bf16 LDS repack (proven), then bf16->fp8 pack, 8B coalesced stores
    short* r = rp + wid * (16 * 72);
    #pragma unroll
    for (int i = 0; i < 4; ++i) {
        #pragma unroll
        for (int j = 0; j < 4; ++j)
            #pragma unroll
            for (int rr = 0; rr < 4; ++rr)
                r[(quad * 4 + rr) * 72 + j * 16 + l16] = f2bf(acc[i][j][rr]);
        #pragma unroll
        for (int h = 0; h < 2; ++h) {
            int rowl = h * 8 + (lane >> 3);
            int colc = (lane & 7) * 8;
            v8s val = *(const v8s*)(r + rowl * 72 + colc);
            int lo = __builtin_amdgcn_cvt_pk_fp8_f32(bf2f(val[0]), bf2f(val[1]), 0, false);
            lo = __builtin_amdgcn_cvt_pk_fp8_f32(bf2f(val[2]), bf2f(val[3]), lo, true);
            int hi = __builtin_amdgcn_cvt_pk_fp8_f32(bf2f(val[4]), bf2f(val[5]), 0, false);
            hi = __builtin_amdgcn_cvt_pk_fp8_f32(bf2f(val[6]), bf2f(val[7]), hi, true);
            int2 st; st.x = lo; st.y = hi;
            *(int2*)(kvl8 + (long)(m0 + wm * 64 + i * 16 + rowl) * 1536 +
                     n0 + wn * 64 + colc) = st;
        }
    }
}

// ---------------- K2: V-part of kvl8 -> Vt8[bh][d(64)][n(1024)] fp8 ----------------
__global__ void transpose_v(const uchar* __restrict__ kvl8, uchar* __restrict__ Vt8) {
    int bh = blockIdx.x, b = bh >> 3, h = bh & 7;
    int n0 = blockIdx.y * 64;
    __shared__ uchar T[64][72];  // rows = d, cols = n_local
    int tid = threadIdx.x;
    #pragma unroll
    for (int it = 0; it < 2; ++it) {
        int nl = (tid >> 3) + it * 32;
        int n = n0 + nl;
        int nc = n < NN ? n : NN - 1;  // clamp: PV has P=0 beyond NN
        int d0 = (tid & 7) * 8;
        ulong_t v = *(const ulong_t*)(kvl8 + ((long)b * NN + nc) * 1536 + DD + h * 64 + d0);
        uchar* vb = (uchar*)&v;
        #pragma unroll
        for (int j = 0; j < 8; ++j) T[d0 + j][nl] = vb[j];
    }
    __syncthreads();
    #pragma unroll
    for (int it = 0; it < 2; ++it) {
        int d = (tid >> 3) + it * 32;
        int ns = (tid & 7) * 8;
        *(ulong_t*)(Vt8 + ((long)bh * 64 + d) * NP + n0 + ns) = *(const ulong_t*)&T[d][ns];
    }
}

// ---------------- K3: fused QK^T -> masked softmax -> PV (fp8 operands) ----------------
#define CST 1036  // cmp row stride (shorts): 518 words/row -> conflict-free frag reads
__global__ __launch_bounds__(256) void attn_fused(const float* __restrict__ q,
                                                  const uchar* __restrict__ kvl8,
                                                  const uchar* __restrict__ Vt8,
                                                  const int* __restrict__ mask,
                                                  float* __restrict__ heads) {
    int b = blockIdx.x, h = blockIdx.y;
    __shared__ __align__(16) uchar qs[32 * 72];       // q fp8, unscaled
    __shared__ __align__(16) short cmp[SS * CST];     // compat bf16; P fp8 in place
    int tid = threadIdx.x, wid = tid >> 6, lane = tid & 63, quad = lane >> 4, l16 = lane & 15;
    for (int i = tid; i < 32 * 64; i += 256) {
        int row = i >> 6, col = i & 63;
        float v = (row < SS) ? q[((long)b * SS + row) * DD + h * 64 + col] : 0.f;
        qs[row * 72 + col] = f2fp8(v);
    }
    __syncthreads();
    // --- QK^T (fp8), /8 applied on f32 output ---
    long af[2][2];
    #pragma unroll
    for (int mt = 0; mt < 2; ++mt)
        #pragma unroll
        for (int ks = 0; ks < 2; ++ks)
            af[mt][ks] = *(const long*)(qs + (mt * 16 + l16) * 72 + ks * 32 + quad * 8);
    for (int t = 0; t < 16; ++t) {
        int nt = wid * 16 + t;
        int n = nt * 16 + l16;
        int nc = n < NN ? n : NN - 1;
        const uchar* kp = kvl8 + ((long)b * NN + nc) * 1536 + h * 64 + quad * 8;
        long b0 = *(const long*)kp;
        long b1 = *(const long*)(kp + 32);
        #pragma unroll
        for (int mt = 0; mt < 2; ++mt) {
            v4f a = {};
            a = __builtin_amdgcn_mfma_f32_16x16x32_fp8_fp8(af[mt][0], b0, a, 0, 0, 0);
            a = __builtin_amdgcn_mfma_f32_16x16x32_fp8_fp8(af[mt][1], b1, a, 0, 0, 0);
            #pragma unroll
            for (int r = 0; r < 4; ++r) {
                int s = mt * 16 + quad * 4 + r;
                if (s < SS) cmp[s * CST + nt * 16 + l16] = f2bf(a[r] * 0.125f);
            }
        }
    }
    __syncthreads();
    // --- masked softmax; P written as fp8 bytes in place ---
    for (int s = wid; s < SS; s += 4) {
        const int* mr = mask + ((long)b * SS + s) * NN;
        float x[16];
        float mx = NEGV;
        #pragma unroll
        for (int i = 0; i < 16; ++i) {
            int n = lane + 64 * i;
            float v = bf2f(cmp[s * CST + n]);
            bool feas = (n < NN) && (mr[n < NN ? n : 0] != 0);
            x[i] = feas ? v : NEGV;
            mx = fmaxf(mx, x[i]);
        }
        for (int off = 32; off; off >>= 1) mx = fmaxf(mx, __shfl_xor(mx, off));
        float sum = 0.f;
        #pragma unroll
        for (int i = 0; i < 16; ++i) { x[i] = __expf(x[i] - mx); sum += x[i]; }
        for (int off = 32; off; off >>= 1) sum += __shfl_xor(sum, off);
        float inv = 1.0f / sum;
        uchar* pr = (uchar*)cmp + (long)s * (CST * 2);
        #pragma unroll
        for (int i = 0; i < 16; ++i) pr[lane + 64 * i] = f2fp8(x[i] * inv);
    }
    __syncthreads();
    // --- PV: A = P fp8 (LDS), B = Vt8 (global, n-contiguous) ---
    int mt = wid & 1, dt0 = (wid >> 1) * 2;
    int srow = mt * 16 + l16; if (srow > SS - 1) srow = SS - 1;
    const uchar* ap = (const uchar*)cmp + (long)srow * (CST * 2) + quad * 8;
    const uchar* vb = Vt8 + (long)(b * HH + h) * 64 * NP;
    v4f acc[2] = {};
    for (int k0 = 0; k0 < NP; k0 += 32) {
        long afr = *(const long*)(ap + k0);
        #pragma unroll
        for (int i = 0; i < 2; ++i) {
            long bfr = *(const long*)(vb + (long)((dt0 + i) * 16 + l16) * NP + k0 + quad * 8);
            acc[i] = __builtin_amdgcn_mfma_f32_16x16x32_fp8_fp8(afr, bfr, acc[i], 0, 0, 0);
        }
    }
    #pragma unroll
    for (int i = 0; i < 2; ++i)
        #pragma unroll
        for (int r = 0; r < 4; ++r) {
            int s = mt * 16 + quad * 4 + r;
            if (s < SS)
                heads[((long)b * SS + s) * DD + h * 64 + (dt0 + i) * 16 + l16] = acc[i][r];
        }
}

// ---------------- K4: glimpse[1280][512] = heads @ W_out (bf16) ----------------
__global__ __launch_bounds__(256) void out_proj(const float* __restrict__ heads,
                                                const short* __restrict__ Wot,
                                                float* __restrict__ glimpse) {
    __shared__ __align__(16) short As[64 * 40], Bs[64 * 40];
    int tid = threadIdx.x;
    int m0 = blockIdx.x * 64, n0 = blockIdx.y * 64;
    int wid = tid >> 6, lane = tid & 63, quad = lane >> 4, l16 = lane & 15;
    int wm = wid & 1, wn = wid >> 1;
    int arow = tid >> 3, akol = (tid & 7) * 4;
    int brow = tid >> 2, bkol = (tid & 3) * 8;
    v4f acc[2][2] = {};
    for (int kk = 0; kk < 512; kk += 32) {
        #pragma unroll
        for (int p = 0; p < 2; ++p) {
            int r = arow + p * 32;
            v4f a = *(const v4f*)(heads + (long)(m0 + r) * 512 + kk + akol);
            short4 s4;
            s4.x = f2bf(a.x); s4.y = f2bf(a.y); s4.z = f2bf(a.z); s4.w = f2bf(a.w);
            *(short4*)(As + r * 40 + akol) = s4;
        }
        *(uint4*)(Bs + brow * 40 + bkol) =
            *(const uint4*)(Wot + (long)(n0 + brow) * 512 + kk + bkol);
        __syncthreads();
        #pragma unroll
        for (int i = 0; i < 2; ++i) {
            v8s af = *(const v8s*)(As + (wm * 32 + i * 16 + l16) * 40 + quad * 8);
            #pragma unroll
            for (int j = 0; j < 2; ++j) {
                v8s bf = *(const v8s*)(Bs + (wn * 32 + j * 16 + l16) * 40 + quad * 8);
                acc[i][j] = __builtin_amdgcn_mfma_f32_16x16x32_bf16(af, bf, acc[i][j], 0, 0, 0);
            }
        }
        __syncthreads();
    }
    #pragma unroll
    for (int i = 0; i < 2; ++i)
        #pragma unroll
        for (int j = 0; j < 2; ++j)
            #pragma unroll
            for (int r = 0; r < 4; ++r)
                glimpse[(long)(m0 + wm * 32 + i * 16 + quad * 4 + r) * 512 +
                        n0 + wn * 32 + j * 16 + l16] = acc[i][j][r];
}

// ---------------- K5: logits = (glimpse . logit_k^T)/sqrt(512)  (fp8) ----------------
__global__ __launch_bounds__(256) void ptr_logits(const float* __restrict__ glimpse,
                                                  const uchar* __restrict__ kvl8,
                                                  float* __restrict__ logits) {
    int b = blockIdx.x, g = blockIdx.y;
    __shared__ __align__(16) uchar Gs[32 * 520];  // fp8, 130 words/row: conflict-free
    int tid = threadIdx.x;
    #pragma unroll
    for (int it = 0; it < 16; ++it) {
        int e = it * 1024 + tid * 4;
        int row = e >> 9, col = e & 511;
        int pk = 0;
        if (row < SS) {
            v4f a = *(const v4f*)(glimpse + ((long)b * SS + row) * 512 + col);
            pk = __builtin_amdgcn_cvt_pk_fp8_f32(a.x, a.y, 0, false);
            pk = __builtin_amdgcn_cvt_pk_fp8_f32(a.z, a.w, pk, true);
        }
        *(int*)(Gs + row * 520 + col) = pk;
    }
    __syncthreads();
    int wid = tid >> 6, lane = tid & 63, quad = lane >> 4, l16 = lane & 15;
    const float scale = 0.04419417382415922f;  // 1/sqrt(512)
    #pragma unroll
    for (int tc = 0; tc < 2; ++tc) {
        int nt = g * 8 + wid * 2 + tc;
        int n = nt * 16 + l16;
        int ncl = n < NN ? n : NN - 1;
        const uchar* kp = kvl8 + ((long)b * NN + ncl) * 1536 + 1024 + quad * 8;
        v4f acc[2] = {};
        for (int k = 0; k < 16; ++k) {
            long bfr = *(const long*)(kp + k * 32);
            #pragma unroll
            for (int m = 0; m < 2; ++m) {
                long afr = *(const long*)(Gs + (m * 16 + l16) * 520 + k * 32 + quad * 8);
                acc[m] = __builtin_amdgcn_mfma_f32_16x16x32_fp8_fp8(afr, bfr, acc[m], 0, 0, 0);
            }
        }
        #pragma unroll
        for (int m = 0; m < 2; ++m)
            #pragma unroll
            for (int r = 0; r < 4; ++r) {
                int s = m * 16 + quad * 4 + r;
                if (s < SS)
                    logits[((long)b * SS + s) * NP + nt * 16 + l16] = acc[m][r] * scale;
            }
    }
}

// ---------------- K6: tanh clip + mask + log_softmax + (s b) transpose ----------------
__global__ __launch_bounds__(256) void logsoftmax_out(const float* __restrict__ logits,
                                                      const int* __restrict__ mask,
                                                      float* __restrict__ out) {
    int row = blockIdx.x;  // b*20 + s
    int b = row / SS, s = row % SS;
    int tid = threadIdx.x;
    __shared__ float red[8];
    int n0 = tid * 4;
    v4f v = *(const v4f*)(logits + (long)row * NP + n0);
    const int* mr = mask + (long)row * NN;
    float x[4];
    float mx = NEGV;
    #pragma unroll
    for (int j = 0; j < 4; ++j) {
        int n = n0 + j;
        float t = 10.f * tanhf(v[j]);
        bool feas = (n < NN) && (mr[n < NN ? n : 0] != 0);
        x[j] = feas ? t : NEGV;
        mx = fmaxf(mx, x[j]);
    }
    for (int off = 32; off; off >>= 1) mx = fmaxf(mx, __shfl_xor(mx, off));
    int wid = tid >> 6, lane = tid & 63;
    if (lane == 0) red[wid] = mx;
    __syncthreads();
    mx = fmaxf(fmaxf(red[0], red[1]), fmaxf(red[2], red[3]));
    float sum = 0.f;
    #pragma unroll
    for (int j = 0; j < 4; ++j) sum += __expf(x[j] - mx);
    for (int off = 32; off; off >>= 1) sum += __shfl_xor(sum, off);
    __syncthreads();
    if (lane == 0) red[4 + wid] = sum;
    __syncthreads();
    sum = red[4] + red[5] + red[6] + red[7];
    float lse = mx + __logf(sum);
    float* orow = out + ((long)s * BB + b) * NN;
    #pragma unroll
    for (int j = 0; j < 4; ++j) {
        int n = n0 + j;
        if (n < NN) orow[n] = x[j] - lse;
    }
}

extern "C" void kernel_launch(void* const* d_in, const int* in_sizes, int n_in,
                              void* d_out, int out_size, void* d_ws, size_t ws_size,
                              hipStream_t stream) {
    const float* emb  = (const float*)d_in[0];
    const float* q    = (const float*)d_in[1];
    const int*   mask = (const int*)d_in[2];
    const float* Wkvl = (const float*)d_in[3];
    const float* Wout = (const float*)d_in[4];
    float* out = (float*)d_out;

    char* ws = (char*)d_ws;
    uchar* kvl8    = (uchar*)ws; ws += (size_t)64000 * 1536;
    uchar* Vt8     = (uchar*)ws; ws += (size_t)512 * 64 * NP;
    uchar* Wt8     = (uchar*)ws; ws += (size_t)1536 * 512;
    uchar* emb8    = (uchar*)ws; ws += (size_t)64000 * 512;
    short* Wot     = (short*)ws; ws += (size_t)512 * 512 * 2;
    float* heads   = (float*)ws; ws += (size_t)BB * SS * DD * 4;
    float* glimpse = (float*)ws; ws += (size_t)BB * SS * DD * 4;
    float* logits  = (float*)ws; ws += (size_t)BB * SS * NP * 4;

    transpose_fp8<<<dim3(48, 16), 256, 0, stream>>>(Wkvl, Wt8, 512, 1536);
    transpose_bf16<<<dim3(16, 16), 256, 0, stream>>>(Wout, Wot, 512, 512);
    cvt_fp8<<<dim3(16000), 256, 0, stream>>>(emb, (int*)emb8, 64000 * 512 / 8);
    gemm_kvl<<<dim3(6000), 256, 0, stream>>>(emb8, Wt8, kvl8);
    transpose_v<<<dim3(512, 16), 256, 0, stream>>>(kvl8, Vt8);
    attn_fused<<<dim3(BB, HH), 256, 0, stream>>>(q, kvl8, Vt8, mask, heads);
    out_proj<<<dim3(20, 8), 256, 0, stream>>>(heads, Wot, glimpse);
    ptr_logits<<<dim3(BB, 8), 256, 0, stream>>>(glimpse, kvl8, logits);
    logsoftmax_out<<<dim3(BB * SS), 256, 0, stream>>>(logits, mask, out);
}

// Round 5
// 351.669 us; speedup vs baseline: 1.5629x; 1.0238x over previous
//
#include <hip/hip_runtime.h>

#define BB 64
#define NN 1000
#define NP 1024
#define DD 512
#define HH 8
#define SS 20
#define NEGV -1e9f

typedef float v4f __attribute__((ext_vector_type(4)));
typedef short v8s __attribute__((ext_vector_type(8)));
typedef int   v8i __attribute__((ext_vector_type(8)));
typedef int   v4i __attribute__((ext_vector_type(4)));
typedef unsigned char uchar;
typedef unsigned long long ulong_t;

static __device__ __forceinline__ short f2bf(float f) {
    unsigned u = __builtin_bit_cast(unsigned, f);
    u = (u + 0x7fffu + ((u >> 16) & 1u)) >> 16;
    return (short)u;
}
static __device__ __forceinline__ float bf2f(short s) {
    unsigned u = ((unsigned)(unsigned short)s) << 16;
    return __builtin_bit_cast(float, u);
}
static __device__ __forceinline__ uchar f2fp8(float f) {
    return (uchar)(__builtin_amdgcn_cvt_pk_fp8_f32(f, 0.f, 0, false) & 0xff);
}

// async global->LDS, 16B per lane; lds dest = wave-uniform base + lane*16
static __device__ __forceinline__ void gld16(const void* g, void* l) {
    __builtin_amdgcn_global_load_lds(
        (const __attribute__((address_space(1))) void*)(g),
        (__attribute__((address_space(3))) void*)(l),
        16, 0, 0);
}

// ---------------- K0 (merged prep): W_kvl^T->fp8, W_out^T->bf16, emb->fp8 ----------------
__global__ void prep(const float* __restrict__ Wkvl, uchar* __restrict__ Wt8,
                     const float* __restrict__ Wout, short* __restrict__ Wot,
                     const float* __restrict__ emb, int* __restrict__ emb8) {
    __shared__ float t[32][33];
    int bid = blockIdx.x, tid = threadIdx.x;
    if (bid < 768) {           // transpose_fp8: W_kvl [512][1536] -> Wt8 [1536][512]
        int c0 = (bid % 48) * 32, r0 = (bid / 48) * 32;
        int x = tid & 31, y = tid >> 5;
        for (int k = 0; k < 32; k += 8)
            t[y + k][x] = Wkvl[(long)(r0 + y + k) * 1536 + c0 + x];
        __syncthreads();
        for (int k = 0; k < 32; k += 8)
            Wt8[(long)(c0 + y + k) * 512 + r0 + x] = f2fp8(t[x][y + k]);
    } else if (bid < 1024) {   // transpose_bf16: W_out [512][512] -> Wot [512][512]
        int bb = bid - 768;
        int c0 = (bb & 15) * 32, r0 = (bb >> 4) * 32;
        int x = tid & 31, y = tid >> 5;
        for (int k = 0; k < 32; k += 8)
            t[y + k][x] = Wout[(long)(r0 + y + k) * 512 + c0 + x];
        __syncthreads();
        for (int k = 0; k < 32; k += 8)
            Wot[(long)(c0 + y + k) * 512 + r0 + x] = f2bf(t[x][y + k]);
    } else {                   // cvt_fp8: emb f32 -> fp8, 8 elems/thread
        int i = (bid - 1024) * 256 + tid;
        long o = (long)i * 8;
        v4f a = *(const v4f*)(emb + o);
        v4f b = *(const v4f*)(emb + o + 4);
        int lo = __builtin_amdgcn_cvt_pk_fp8_f32(a.x, a.y, 0, false);
        lo = __builtin_amdgcn_cvt_pk_fp8_f32(a.z, a.w, lo, true);
        int hi = __builtin_amdgcn_cvt_pk_fp8_f32(b.x, b.y, 0, false);
        hi = __builtin_amdgcn_cvt_pk_fp8_f32(b.z, b.w, hi, true);
        int2 r; r.x = lo; r.y = hi;
        *(int2*)(emb8 + i * 2) = r;
    }
}

// ---------------- K1: kvl8[64000][1536] = emb8 @ Wt8  (MX-fp8, unit scales) ----------------
// 128x128 tile, BK=128, gld16 + XOR swizzle, fp8 out, XCD id swizzle, rp aliased on As.
__global__ __launch_bounds__(256) void gemm_kvl(const uchar* __restrict__ emb8,
                                                const uchar* __restrict__ Wt8,
                                                uchar* __restrict__ kvl8) {
    __shared__ __align__(16) uchar As[128 * 128];
    __shared__ __align__(16) uchar Bs[128 * 128];
    int tid = threadIdx.x;
    int id = blockIdx.x;
    int m_idx, n_idx;
    if (id < 5952) { int g = id / 96, r = id % 96; m_idx = g * 8 + (r & 7); n_idx = r >> 3; }
    else { int t = id - 5952; m_idx = 496 + (t & 3); n_idx = t >> 2; }
    int n0 = n_idx * 128, m0 = m_idx * 128;
    int wid = tid >> 6, lane = tid & 63, quad = lane >> 4, l16 = lane & 15;
    int wm = wid & 1, wn = wid >> 1;
    v4f acc[4][4] = {};
    const uchar* Ag = emb8 + (long)m0 * 512;
    const uchar* Bg = Wt8 + (long)n0 * 512;
    int rsub = lane >> 3;
    int kc = ((lane & 7) ^ rsub) * 16;
    for (int kk = 0; kk < 512; kk += 128) {
        #pragma unroll
        for (int p = 0; p < 4; ++p) {
            int rl = wid * 32 + p * 8;
            gld16(Ag + (long)(rl + rsub) * 512 + kk + kc, As + rl * 128);
            gld16(Bg + (long)(rl + rsub) * 512 + kk + kc, Bs + rl * 128);
        }
        __syncthreads();
        v8i af[4], bf[4];
        #pragma unroll
        for (int i = 0; i < 4; ++i) {
            int m = wm * 64 + i * 16 + l16;
            int c0 = (quad * 2) ^ (m & 7), c1 = (quad * 2 + 1) ^ (m & 7);
            v4i lo = *(const v4i*)(As + m * 128 + c0 * 16);
            v4i hi = *(const v4i*)(As + m * 128 + c1 * 16);
            af[i] = __builtin_shufflevector(lo, hi, 0, 1, 2, 3, 4, 5, 6, 7);
        }
        #pragma unroll
        for (int j = 0; j < 4; ++j) {
            int n = wn * 64 + j * 16 + l16;
            int c0 = (quad * 2) ^ (n & 7), c1 = (quad * 2 + 1) ^ (n & 7);
            v4i lo = *(const v4i*)(Bs + n * 128 + c0 * 16);
            v4i hi = *(const v4i*)(Bs + n * 128 + c1 * 16);
            bf[j] = __builtin_shufflevector(lo, hi, 0, 1, 2, 3, 4, 5, 6, 7);
        }
        #pragma unroll
        for (int i = 0; i < 4; ++i)
            #pragma unroll
            for (int j = 0; j < 4; ++j)
                acc[i][j] = __builtin_amdgcn_mfma_scale_f32_16x16x128_f8f6f4(
                    af[i], bf[j], acc[i][j], 0, 0, 0, 0x7f7f7f7f, 0, 0x7f7f7f7f);
        __syncthreads();
    }
    // epilogue: rp aliased onto As (safe: final barrier above; region is wave-private)
    short* rp = (short*)As;
    short* r = rp + wid * (16 * 72);
    #pragma unroll
    for (int i = 0; i < 4; ++i) {
        #pragma unroll
        for (int j = 0; j < 4; ++j)
            #pragma unroll
            for (int rr = 0; rr < 4; ++rr)
                r[(quad * 4 + rr) * 72 + j * 16 + l16] = f2bf(acc[i][j][rr]);
        #pragma unroll
        for (int h = 0; h < 2; ++h) {
            int rowl = h * 8 + (lane >> 3);
            int colc = (lane & 7) * 8;
            v8s val = *(const v8s*)(r + rowl * 72 + colc);
            int lo = __builtin_amdgcn_cvt_pk_fp8_f32(bf2f(val[0]), bf2f(val[1]), 0, false);
            lo = __builtin_amdgcn_cvt_pk_fp8_f32(bf2f(val[2]), bf2f(val[3]), lo, true);
            int hi = __builtin_amdgcn_cvt_pk_fp8_f32(bf2f(val[4]), bf2f(val[5]), 0, false);
            hi = __builtin_amdgcn_cvt_pk_fp8_f32(bf2f(val[6]), bf2f(val[7]), hi, true);
            int2 st; st.x = lo; st.y = hi;
            *(int2*)(kvl8 + (long)(m0 + wm * 64 + i * 16 + rowl) * 1536 +
                     n0 + wn * 64 + colc) = st;
        }
    }
}

// ---------------- K2: V-part of kvl8 -> Vt8[bh][d(64)][n(1024)] fp8 ----------------
__global__ void transpose_v(const uchar* __restrict__ kvl8, uchar* __restrict__ Vt8) {
    int bh = blockIdx.x, b = bh >> 3, h = bh & 7;
    int n0 = blockIdx.y * 64;
    __shared__ uchar T[64][72];
    int tid = threadIdx.x;
    #pragma unroll
    for (int it = 0; it < 2; ++it) {
        int nl = (tid >> 3) + it * 32;
        int n = n0 + nl;
        int nc = n < NN ? n : NN - 1;  // clamp: PV has P=0 beyond NN
        int d0 = (tid & 7) * 8;
        ulong_t v = *(const ulong_t*)(kvl8 + ((long)b * NN + nc) * 1536 + DD + h * 64 + d0);
        uchar* vb = (uchar*)&v;
        #pragma unroll
        for (int j = 0; j < 8; ++j) T[d0 + j][nl] = vb[j];
    }
    __syncthreads();
    #pragma unroll
    for (int it = 0; it < 2; ++it) {
        int d = (tid >> 3) + it * 32;
        int ns = (tid & 7) * 8;
        *(ulong_t*)(Vt8 + ((long)bh * 64 + d) * NP + n0 + ns) = *(const ulong_t*)&T[d][ns];
    }
}

// ---------------- K3: fused QK^T -> masked softmax -> PV (fp8, 512 threads) ----------------
#define CST 1036  // cmp row stride (shorts): 518 words/row -> conflict-free frag reads
__global__ __launch_bounds__(512) void attn_fused(const float* __restrict__ q,
                                                  const uchar* __restrict__ kvl8,
                                                  const uchar* __restrict__ Vt8,
                                                  const int* __restrict__ mask,
                                                  float* __restrict__ heads) {
    int b = blockIdx.x, h = blockIdx.y;
    __shared__ __align__(16) uchar qs[32 * 72];
    __shared__ __align__(16) short cmp[SS * CST];
    int tid = threadIdx.x, wid = tid >> 6, lane = tid & 63, quad = lane >> 4, l16 = lane & 15;
    for (int i = tid; i < 32 * 64; i += 512) {
        int row = i >> 6, col = i & 63;
        float v = (row < SS) ? q[((long)b * SS + row) * DD + h * 64 + col] : 0.f;
        qs[row * 72 + col] = f2fp8(v);
    }
    __syncthreads();
    // --- QK^T (fp8), /8 on f32 output ---
    long af[2][2];
    #pragma unroll
    for (int mt = 0; mt < 2; ++mt)
        #pragma unroll
        for (int ks = 0; ks < 2; ++ks)
            af[mt][ks] = *(const long*)(qs + (mt * 16 + l16) * 72 + ks * 32 + quad * 8);
    for (int t = 0; t < 8; ++t) {
        int nt = wid * 8 + t;
        int n = nt * 16 + l16;
        int nc = n < NN ? n : NN - 1;
        const uchar* kp = kvl8 + ((long)b * NN + nc) * 1536 + h * 64 + quad * 8;
        long b0 = *(const long*)kp;
        long b1 = *(const long*)(kp + 32);
        #pragma unroll
        for (int mt = 0; mt < 2; ++mt) {
            v4f a = {};
            a = __builtin_amdgcn_mfma_f32_16x16x32_fp8_fp8(af[mt][0], b0, a, 0, 0, 0);
            a = __builtin_amdgcn_mfma_f32_16x16x32_fp8_fp8(af[mt][1], b1, a, 0, 0, 0);
            #pragma unroll
            for (int r = 0; r < 4; ++r) {
                int s = mt * 16 + quad * 4 + r;
                if (s < SS) cmp[s * CST + nt * 16 + l16] = f2bf(a[r] * 0.125f);
            }
        }
    }
    __syncthreads();
    // --- masked softmax; P written as fp8 bytes in place ---
    for (int s = wid; s < SS; s += 8) {
        const int* mr = mask + ((long)b * SS + s) * NN;
        float x[16];
        float mx = NEGV;
        #pragma unroll
        for (int i = 0; i < 16; ++i) {
            int n = lane + 64 * i;
            float v = bf2f(cmp[s * CST + n]);
            bool feas = (n < NN) && (mr[n < NN ? n : 0] != 0);
            x[i] = feas ? v : NEGV;
            mx = fmaxf(mx, x[i]);
        }
        for (int off = 32; off; off >>= 1) mx = fmaxf(mx, __shfl_xor(mx, off));
        float sum = 0.f;
        #pragma unroll
        for (int i = 0; i < 16; ++i) { x[i] = __expf(x[i] - mx); sum += x[i]; }
        for (int off = 32; off; off >>= 1) sum += __shfl_xor(sum, off);
        float inv = 1.0f / sum;
        uchar* pr = (uchar*)cmp + (long)s * (CST * 2);
        #pragma unroll
        for (int i = 0; i < 16; ++i) pr[lane + 64 * i] = f2fp8(x[i] * inv);
    }
    __syncthreads();
    // --- PV: 8 waves, each one (mt, d-tile) pair ---
    int mt = wid & 1, dt = wid >> 1;  // dt in 0..3
    int srow = mt * 16 + l16; if (srow > SS - 1) srow = SS - 1;
    const uchar* ap = (const uchar*)cmp + (long)srow * (CST * 2) + quad * 8;
    const uchar* vb = Vt8 + (long)(b * HH + h) * 64 * NP;
    v4f acc = {};
    for (int k0 = 0; k0 < NP; k0 += 32) {
        long afr = *(const long*)(ap + k0);
        long bfr = *(const long*)(vb + (long)(dt * 16 + l16) * NP + k0 + quad * 8);
        acc = __builtin_amdgcn_mfma_f32_16x16x32_fp8_fp8(afr, bfr, acc, 0, 0, 0);
    }
    #pragma unroll
    for (int r = 0; r < 4; ++r) {
        int s = mt * 16 + quad * 4 + r;
        if (s < SS)
            heads[((long)b * SS + s) * DD + h * 64 + dt * 16 + l16] = acc[r];
    }
}

// ---------------- K4: glimpse[1280][512] = heads @ W_out (bf16) ----------------
__global__ __launch_bounds__(256) void out_proj(const float* __restrict__ heads,
                                                const short* __restrict__ Wot,
                                                float* __restrict__ glimpse) {
    __shared__ __align__(16) short As[64 * 40], Bs[64 * 40];
    int tid = threadIdx.x;
    int m0 = blockIdx.x * 64, n0 = blockIdx.y * 64;
    int wid = tid >> 6, lane = tid & 63, quad = lane >> 4, l16 = lane & 15;
    int wm = wid & 1, wn = wid >> 1;
    int arow = tid >> 3, akol = (tid & 7) * 4;
    int brow = tid >> 2, bkol = (tid & 3) * 8;
    v4f acc[2][2] = {};
    for (int kk = 0; kk < 512; kk += 32) {
        #pragma unroll
        for (int p = 0; p < 2; ++p) {
            int r = arow + p * 32;
            v4f a = *(const v4f*)(heads + (long)(m0 + r) * 512 + kk + akol);
            short4 s4;
            s4.x = f2bf(a.x); s4.y = f2bf(a.y); s4.z = f2bf(a.z); s4.w = f2bf(a.w);
            *(short4*)(As + r * 40 + akol) = s4;
        }
        *(uint4*)(Bs + brow * 40 + bkol) =
            *(const uint4*)(Wot + (long)(n0 + brow) * 512 + kk + bkol);
        __syncthreads();
        #pragma unroll
        for (int i = 0; i < 2; ++i) {
            v8s af = *(const v8s*)(As + (wm * 32 + i * 16 + l16) * 40 + quad * 8);
            #pragma unroll
            for (int j = 0; j < 2; ++j) {
                v8s bf = *(const v8s*)(Bs + (wn * 32 + j * 16 + l16) * 40 + quad * 8);
                acc[i][j] = __builtin_amdgcn_mfma_f32_16x16x32_bf16(af, bf, acc[i][j], 0, 0, 0);
            }
        }
        __syncthreads();
    }
    #pragma unroll
    for (int i = 0; i < 2; ++i)
        #pragma unroll
        for (int j = 0; j < 2; ++j)
            #pragma unroll
            for (int r = 0; r < 4; ++r)
                glimpse[(long)(m0 + wm * 32 + i * 16 + quad * 4 + r) * 512 +
                        n0 + wn * 32 + j * 16 + l16] = acc[i][j][r];
}

// ---------------- K5: logits = (glimpse . logit_k^T)/sqrt(512)  (fp8) ----------------
__global__ __launch_bounds__(256) void ptr_logits(const float* __restrict__ glimpse,
                                                  const uchar* __restrict__ kvl8,
                                                  float* __restrict__ logits) {
    int b = blockIdx.x, g = blockIdx.y;  // g in 0..15, one n-tile per wave
    __shared__ __align__(16) uchar Gs[32 * 520];
    int tid = threadIdx.x;
    #pragma unroll
    for (int it = 0; it < 16; ++it) {
        int e = it * 1024 + tid * 4;
        int row = e >> 9, col = e & 511;
        int pk = 0;
        if (row < SS) {
            v4f a = *(const v4f*)(glimpse + ((long)b * SS + row) * 512 + col);
            pk = __builtin_amdgcn_cvt_pk_fp8_f32(a.x, a.y, 0, false);
            pk = __builtin_amdgcn_cvt_pk_fp8_f32(a.z, a.w, pk, true);
        }
        *(int*)(Gs + row * 520 + col) = pk;
    }
    __syncthreads();
    int wid = tid >> 6, lane = tid & 63, quad = lane >> 4, l16 = lane & 15;
    const float scale = 0.04419417382415922f;  // 1/sqrt(512)
    int nt = g * 4 + wid;
    int n = nt * 16 + l16;
    int ncl = n < NN ? n : NN - 1;
    const uchar* kp = kvl8 + ((long)b * NN + ncl) * 1536 + 1024 + quad * 8;
    v4f acc[2] = {};
    for (int k = 0; k < 16; ++k) {
        long bfr = *(const long*)(kp + k * 32);
        #pragma unroll
        for (int m = 0; m < 2; ++m) {
            long afr = *(const long*)(Gs + (m * 16 + l16) * 520 + k * 32 + quad * 8);
            acc[m] = __builtin_amdgcn_mfma_f32_16x16x32_fp8_fp8(afr, bfr, acc[m], 0, 0, 0);
        }
    }
    #pragma unroll
    for (int m = 0; m < 2; ++m)
        #pragma unroll
        for (int r = 0; r < 4; ++r) {
            int s = m * 16 + quad * 4 + r;
            if (s < SS)
                logits[((long)b * SS + s) * NP + nt * 16 + l16] = acc[m][r] * scale;
        }
}

// ---------------- K6: tanh clip + mask + log_softmax + (s b) transpose ----------------
__global__ __launch_bounds__(256) void logsoftmax_out(const float* __restrict__ logits,
                                                      const int* __restrict__ mask,
                                                      float* __restrict__ out) {
    int row = blockIdx.x;  // b*20 + s
    int b = row / SS, s = row % SS;
    int tid = threadIdx.x;
    __shared__ float red[8];
    int n0 = tid * 4;
    v4f v = *(const v4f*)(logits + (long)row * NP + n0);
    const int* mr = mask + (long)row * NN;
    float x[4];
    float mx = NEGV;
    #pragma unroll
    for (int j = 0; j < 4; ++j) {
        int n = n0 + j;
        float t = 10.f * tanhf(v[j]);
        bool feas = (n < NN) && (mr[n < NN ? n : 0] != 0);
        x[j] = feas ? t : NEGV;
        mx = fmaxf(mx, x[j]);
    }
    for (int off = 32; off; off >>= 1) mx = fmaxf(mx, __shfl_xor(mx, off));
    int wid = tid >> 6, lane = tid & 63;
    if (lane == 0) red[wid] = mx;
    __syncthreads();
    mx = fmaxf(fmaxf(red[0], red[1]), fmaxf(red[2], red[3]));
    float sum = 0.f;
    #pragma unroll
    for (int j = 0; j < 4; ++j) sum += __expf(x[j] - mx);
    for (int off = 32; off; off >>= 1) sum += __shfl_xor(sum, off);
    __syncthreads();
    if (lane == 0) red[4 + wid] = sum;
    __syncthreads();
    sum = red[4] + red[5] + red[6] + red[7];
    float lse = mx + __logf(sum);
    float* orow = out + ((long)s * BB + b) * NN;
    #pragma unroll
    for (int j = 0; j < 4; ++j) {
        int n = n0 + j;
        if (n < NN) orow[n] = x[j] - lse;
    }
}

extern "C" void kernel_launch(void* const* d_in, const int* in_sizes, int n_in,
                              void* d_out, int out_size, void* d_ws, size_t ws_size,
                              hipStream_t stream) {
    const float* emb  = (const float*)d_in[0];
    const float* q    = (const float*)d_in[1];
    const int*   mask = (const int*)d_in[2];
    const float* Wkvl = (const float*)d_in[3];
    const float* Wout = (const float*)d_in[4];
    float* out = (float*)d_out;

    char* ws = (char*)d_ws;
    uchar* kvl8    = (uchar*)ws; ws += (size_t)64000 * 1536;
    uchar* Vt8     = (uchar*)ws; ws += (size_t)512 * 64 * NP;
    uchar* Wt8     = (uchar*)ws; ws += (size_t)1536 * 512;
    uchar* emb8    = (uchar*)ws; ws += (size_t)64000 * 512;
    short* Wot     = (short*)ws; ws += (size_t)512 * 512 * 2;
    float* heads   = (float*)ws; ws += (size_t)BB * SS * DD * 4;
    float* glimpse = (float*)ws; ws += (size_t)BB * SS * DD * 4;
    float* logits  = (float*)ws; ws += (size_t)BB * SS * NP * 4;

    prep<<<dim3(1024 + 16000), 256, 0, stream>>>(Wkvl, Wt8, Wout, Wot, emb, (int*)emb8);
    gemm_kvl<<<dim3(6000), 256, 0, stream>>>(emb8, Wt8, kvl8);
    transpose_v<<<dim3(512, 16), 256, 0, stream>>>(kvl8, Vt8);
    attn_fused<<<dim3(BB, HH), 512, 0, stream>>>(q, kvl8, Vt8, mask, heads);
    out_proj<<<dim3(20, 8), 256, 0, stream>>>(heads, Wot, glimpse);
    ptr_logits<<<dim3(BB, 16), 256, 0, stream>>>(glimpse, kvl8, logits);
    logsoftmax_out<<<dim3(BB * SS), 256, 0, stream>>>(logits, mask, out);
}